// Round 7
// baseline (447.125 us; speedup 1.0000x reference)
//
#include <hip/hip_runtime.h>
#include <hip/hip_bf16.h>
#include <math.h>

typedef short short8 __attribute__((ext_vector_type(8)));
typedef float f32x4 __attribute__((ext_vector_type(4)));
typedef __hip_bfloat16 bf16;

// problem constants
#define KN 10
#define KC 512
#define KHW 1600
#define KH 40
#define KOC 128
#define KPW 42   // padded spatial (40+2)
#define KM 1280  // stacked M: 9 conv taps * 128 + 128 shortcut

// ---------------- block reduction helpers (fp64) ----------------
__device__ __forceinline__ double blockReduceSumD(double v) {
  __shared__ double tmpS[8];
  int lane = threadIdx.x & 63, wv = threadIdx.x >> 6;
  #pragma unroll
  for (int o = 32; o > 0; o >>= 1) v += __shfl_down(v, o);
  if (lane == 0) tmpS[wv] = v;
  __syncthreads();
  if (threadIdx.x == 0) {
    int nw = (blockDim.x + 63) >> 6;
    double s = 0;
    for (int i = 0; i < nw; i++) s += tmpS[i];
    tmpS[0] = s;
  }
  __syncthreads();
  double r = tmpS[0];
  __syncthreads();
  return r;
}

__device__ __forceinline__ double blockReduceMinD(double v) {
  __shared__ double tmpMn[8];
  int lane = threadIdx.x & 63, wv = threadIdx.x >> 6;
  #pragma unroll
  for (int o = 32; o > 0; o >>= 1) v = fmin(v, __shfl_down(v, o));
  if (lane == 0) tmpMn[wv] = v;
  __syncthreads();
  if (threadIdx.x == 0) {
    int nw = (blockDim.x + 63) >> 6;
    double s = tmpMn[0];
    for (int i = 1; i < nw; i++) s = fmin(s, tmpMn[i]);
    tmpMn[0] = s;
  }
  __syncthreads();
  double r = tmpMn[0];
  __syncthreads();
  return r;
}

__device__ __forceinline__ double blockReduceMaxD(double v) {
  __shared__ double tmpMx[8];
  int lane = threadIdx.x & 63, wv = threadIdx.x >> 6;
  #pragma unroll
  for (int o = 32; o > 0; o >>= 1) v = fmax(v, __shfl_down(v, o));
  if (lane == 0) tmpMx[wv] = v;
  __syncthreads();
  if (threadIdx.x == 0) {
    int nw = (blockDim.x + 63) >> 6;
    double s = tmpMx[0];
    for (int i = 1; i < nw; i++) s = fmax(s, tmpMx[i]);
    tmpMx[0] = s;
  }
  __syncthreads();
  double r = tmpMx[0];
  __syncthreads();
  return r;
}

// ---------------- small chain (fp64 for argsort stability) ----------------

// phase 1: partial sum of squares over a c-chunk
__global__ void k_rnormp(const float* __restrict__ feats, double* __restrict__ ps) {
  int t = blockIdx.x * 256 + threadIdx.x;
  if (t >= KN * KHW) return;
  int ci = blockIdx.y;
  int n = t / KHW, k = t % KHW;
  const float* p = feats + (size_t)n * KC * KHW + (size_t)ci * 128 * KHW + k;
  double s = 0.0;
  for (int c = 0; c < 128; ++c) { double v = p[(size_t)c * KHW]; s += v * v; }
  ps[(size_t)ci * KN * KHW + t] = s;
}

// phase 2: combine 4 partials -> rnorm
__global__ void k_rnormc(const double* __restrict__ ps, double* __restrict__ rnorm) {
  int t = blockIdx.x * 256 + threadIdx.x;
  if (t >= KN * KHW) return;
  double s = ps[t] + ps[KN * KHW + t] + ps[2 * KN * KHW + t] + ps[3 * KN * KHW + t];
  double nn = sqrt(s);
  if (nn < 1e-12) nn = 1e-12;
  rnorm[t] = 1.0 / nn;
}

// NFT[n,k,c] = bf16(feats[n,c,k] * rnorm[n,k])
__global__ void k_nft(const float* __restrict__ feats, const double* __restrict__ rnorm,
                      bf16* __restrict__ NFT) {
  __shared__ float T[32][33];
  int n = blockIdx.z, k0 = blockIdx.x * 32, c0 = blockIdx.y * 32;
  int tx = threadIdx.x, ty = threadIdx.y;
  const float* fb = feats + ((size_t)n * KC + c0) * KHW + k0;
  #pragma unroll
  for (int ii = 0; ii < 4; ii++) {
    int cl = ty * 4 + ii;
    T[cl][tx] = fb[(size_t)cl * KHW + tx];
  }
  __syncthreads();
  bf16* ob = NFT + ((size_t)n * KHW + k0) * KC + c0;
  #pragma unroll
  for (int ii = 0; ii < 4; ii++) {
    int kl = ty * 4 + ii;
    float r = (float)rnorm[n * KHW + k0 + kl];
    ob[(size_t)kl * KC + tx] = __float2bfloat16(T[tx][kl] * r);
  }
}

__global__ void k_sivpre(const float* __restrict__ feats, const float* __restrict__ sism,
                         const double* __restrict__ rnorm, double* __restrict__ vbuf) {
  int b = blockIdx.x;
  int n = b / KC, c = b % KC;
  const float* f = feats + ((size_t)n * KC + c) * KHW;
  const float* s = sism + (size_t)n * KHW;
  const double* r = rnorm + (size_t)n * KHW;
  double acc = 0;
  for (int k = threadIdx.x; k < KHW; k += 256) acc += (double)f[k] * r[k] * (double)s[k];
  acc = blockReduceSumD(acc);
  if (threadIdx.x == 0) vbuf[b] = acc / (double)KHW;
}

__global__ void k_sivnorm(const double* __restrict__ vbuf, double* __restrict__ SIV) {
  int n = blockIdx.x;
  double v = vbuf[n * KC + threadIdx.x];
  double s2 = blockReduceSumD(v * v);
  double nn = sqrt(s2);
  if (nn < 1e-12) nn = 1e-12;
  SIV[n * KC + threadIdx.x] = v / nn;
}

// cm[n,m,k] = rnorm[n,k] * sum_c feats[n,c,k]*SIV[m,c]; feats read ONCE (acc over all m)
__global__ void k_cmA(const float* __restrict__ feats, const double* __restrict__ rnorm,
                      const double* __restrict__ SIV, double* __restrict__ cm) {
  __shared__ double sv[KN * KC];
  int n = blockIdx.y;
  for (int t = threadIdx.x; t < KN * KC; t += 256) sv[t] = SIV[t];
  __syncthreads();
  int k = blockIdx.x * 256 + threadIdx.x;
  if (k >= KHW) return;
  const float* f = feats + (size_t)n * KC * KHW + k;
  double acc[KN];
  #pragma unroll
  for (int m = 0; m < KN; m++) acc[m] = 0.0;
  for (int c = 0; c < KC; ++c) {
    double fv = f[(size_t)c * KHW];
    #pragma unroll
    for (int m = 0; m < KN; m++) acc[m] += fv * sv[m * KC + c];
  }
  double r = rnorm[n * KHW + k];
  #pragma unroll
  for (int m = 0; m < KN; m++) cm[((size_t)n * KN + m) * KHW + k] = acc[m] * r;
}

__global__ void k_cmnorm(double* __restrict__ cm) {
  double* row = cm + (size_t)blockIdx.x * KHW;
  double s = 0;
  for (int k = threadIdx.x; k < KHW; k += 256) { double v = row[k]; s += v * v; }
  s = blockReduceSumD(s);
  double nn = sqrt(s);
  if (nn < 1e-12) nn = 1e-12;
  double rn = 1.0 / nn;
  for (int k = threadIdx.x; k < KHW; k += 256) row[k] *= rn;
}

__global__ void k_s(const double* __restrict__ cm, double* __restrict__ S) {
  int t = blockIdx.x * 256 + threadIdx.x;
  if (t >= KN * KHW) return;
  int n = t / KHW, k = t % KHW;
  double s = 0;
  #pragma unroll
  for (int m = 0; m < KN; m++) s += cm[((size_t)n * KN + m) * KHW + k];
  S[t] = s;
}

__global__ void k_t(const double* __restrict__ cm, const double* __restrict__ S,
                    double* __restrict__ tbuf) {
  int b = blockIdx.x;
  int n = b / KN;
  const double* row = cm + (size_t)b * KHW;
  const double* Sv = S + (size_t)n * KHW;
  double acc = 0;
  for (int k = threadIdx.x; k < KHW; k += 256) acc += row[k] * Sv[k];
  acc = blockReduceSumD(acc);
  if (threadIdx.x == 0) tbuf[b] = acc;
}

__global__ void k_wv(const double* __restrict__ tbuf, double* __restrict__ wv) {
  int n = threadIdx.x;
  if (n >= KN) return;
  double v[KN], mx = -1e300;
  #pragma unroll
  for (int m = 0; m < KN; m++) { v[m] = tbuf[n * KN + m]; mx = fmax(mx, v[m]); }
  double s = 0;
  #pragma unroll
  for (int m = 0; m < KN; m++) { v[m] = exp(v[m] - mx); s += v[m]; }
  #pragma unroll
  for (int m = 0; m < KN; m++) wv[n * KN + m] = v[m] / s;
}

__global__ void k_csa(const double* __restrict__ cm, const double* __restrict__ wv,
                      double* __restrict__ CSAd, float* __restrict__ CSAf) {
  __shared__ double w[KN];
  int n = blockIdx.x, tid = threadIdx.x;
  if (tid < KN) w[tid] = wv[n * KN + tid];
  __syncthreads();
  double v[7];
  int cnt = 0;
  double lmin = 1e300, lmax = -1e300;
  for (int k = tid; k < KHW; k += 256) {
    double a = 0;
    #pragma unroll
    for (int m = 0; m < KN; m++) a += cm[((size_t)n * KN + m) * KHW + k] * w[m];
    v[cnt++] = a;
    lmin = fmin(lmin, a);
    lmax = fmax(lmax, a);
  }
  double mn = blockReduceMinD(lmin);
  double mx = blockReduceMaxD(lmax);
  double inv = 1.0 / (mx - mn + 1e-12);
  cnt = 0;
  for (int k = tid; k < KHW; k += 256) {
    double nv = (v[cnt++] - mn) * inv;
    CSAd[(size_t)n * KHW + k] = nv;
    CSAf[(size_t)n * KHW + k] = (float)nv;
  }
}

// rank-based stable descending argsort: idx[rank[i]] = i
// rank[i] = #{j: key[j] > key[i]} + #{j<i: key[j] == key[i]}  == stable argsort(-CSA)
__global__ void k_rank(const double* __restrict__ CSAd, int* __restrict__ idx) {
  __shared__ double key[KHW];
  int n = blockIdx.y;
  for (int i = threadIdx.x; i < KHW; i += 256) key[i] = CSAd[(size_t)n * KHW + i];
  __syncthreads();
  int i = blockIdx.x * 256 + threadIdx.x;
  if (i >= KHW) return;
  double ki = key[i];
  int r = 0;
  #pragma unroll 4
  for (int j = 0; j < KHW; j++) {
    double kj = key[j];
    r += (kj > ki) || (kj == ki && j < i);
  }
  idx[n * KHW + r] = i;
}

// ---------------- stacked weights (n-independent): w1s[(tau,o)][i] ----------------
__global__ void k_prepw1s(const float* __restrict__ w1, const float* __restrict__ wsc,
                          bf16* __restrict__ w1s) {
  int t = blockIdx.x * 256 + threadIdx.x;   // over KM*KHW
  int m = t / KHW, i = t % KHW;
  int tau = m >> 7, o = m & 127;
  float v = (tau < 9) ? w1[((size_t)o * KHW + i) * 9 + tau]
                      : wsc[(size_t)o * KHW + i];
  w1s[t] = __float2bfloat16(v);
}

__global__ void k_prepw2(const float* __restrict__ w2, bf16* __restrict__ w2p) {
  int t = blockIdx.x * 256 + threadIdx.x;
  if (t >= KOC * 9 * KOC) return;
  int o = t / (9 * KOC), r = t % (9 * KOC);
  int s = r / KOC, i = r % KOC;
  w2p[t] = __float2bfloat16(w2[(size_t)o * 9 * KOC + (size_t)i * 9 + s]);
}

// ---------------- NF column gather from NFT rows: NFcg[n][c][i] = NFT[n][idx[i]][c] ----------------
__global__ void k_gath2(const short* __restrict__ NFT, const int* __restrict__ idx,
                        short* __restrict__ NFcg) {
  __shared__ short T[32][33];
  int i0 = blockIdx.x * 32, c0 = blockIdx.y * 32, n = blockIdx.z;
  int tx = threadIdx.x, ty = threadIdx.y;
  #pragma unroll
  for (int ii = 0; ii < 4; ii++) {
    int row = ty * 4 + ii;
    int id = idx[n * KHW + i0 + row];
    T[row][tx] = NFT[((size_t)n * KHW + id) * KC + c0 + tx];
  }
  __syncthreads();
  #pragma unroll
  for (int ii = 0; ii < 4; ii++) {
    int cl = ty * 4 + ii;
    NFcg[((size_t)n * KC + c0 + cl) * KHW + i0 + tx] = T[tx][cl];
  }
}

// ---------------- GEMM1: U[n][m][c] = sum_i w1s[m,i] * NFcg[n,c,i] ----------------
__global__ __launch_bounds__(256) void k_gemmU(const short* __restrict__ w1s,
                                               const short* __restrict__ NFcg,
                                               bf16* __restrict__ U) {
  __shared__ short smem[128 * 136];          // aliased As/Bs then Cs
  short* As = smem;                          // [128][40]
  short* Bs = smem + 128 * 40;               // [128][40]
  short* Cs = smem;                          // [128][136]
  int n = blockIdx.z;
  int m0 = blockIdx.x * 128, c0 = blockIdx.y * 128;
  int tid = threadIdx.x, lane = tid & 63, wave = tid >> 6;
  int quad = lane >> 4, l15 = lane & 15;
  int wm = (wave & 1) * 64, wn = (wave >> 1) * 64;
  int ar = tid >> 2, ko = (tid & 3) * 8;
  const short* Bb = NFcg + (size_t)n * KC * KHW;
  const short* pa0 = w1s + (size_t)(m0 + ar) * KHW + ko;
  const short* pa1 = w1s + (size_t)(m0 + ar + 64) * KHW + ko;
  const short* pb0 = Bb + (size_t)(c0 + ar) * KHW + ko;
  const short* pb1 = Bb + (size_t)(c0 + ar + 64) * KHW + ko;
  f32x4 acc[4][4] = {};
  for (int k0 = 0; k0 < KHW; k0 += 32) {
    __syncthreads();
    *(float4*)&As[ar * 40 + ko]        = *(const float4*)&pa0[k0];
    *(float4*)&As[(ar + 64) * 40 + ko] = *(const float4*)&pa1[k0];
    *(float4*)&Bs[ar * 40 + ko]        = *(const float4*)&pb0[k0];
    *(float4*)&Bs[(ar + 64) * 40 + ko] = *(const float4*)&pb1[k0];
    __syncthreads();
    short8 a[4], b[4];
    #pragma unroll
    for (int t = 0; t < 4; t++) a[t] = *(const short8*)&As[(wm + t * 16 + l15) * 40 + quad * 8];
    #pragma unroll
    for (int t = 0; t < 4; t++) b[t] = *(const short8*)&Bs[(wn + t * 16 + l15) * 40 + quad * 8];
    #pragma unroll
    for (int ti = 0; ti < 4; ti++)
      #pragma unroll
      for (int tj = 0; tj < 4; tj++)
        acc[ti][tj] = __builtin_amdgcn_mfma_f32_16x16x32_bf16(a[ti], b[tj], acc[ti][tj], 0, 0, 0);
  }
  __syncthreads();   // frag reads done; reuse smem as Cs
  #pragma unroll
  for (int ti = 0; ti < 4; ti++) {
    int lr = wm + ti * 16 + quad * 4;
    #pragma unroll
    for (int tj = 0; tj < 4; tj++) {
      int lc = wn + tj * 16 + l15;
      #pragma unroll
      for (int r = 0; r < 4; r++)
        *(bf16*)&Cs[(lr + r) * 136 + lc] = __float2bfloat16(acc[ti][tj][r]);
    }
  }
  __syncthreads();
  #pragma unroll
  for (int pass = 0; pass < 8; pass++) {
    int row = pass * 16 + (tid >> 4);
    int col = (tid & 15) * 8;
    *(float4*)&U[((size_t)n * KM + m0 + row) * KC + c0 + col] =
        *(const float4*)&Cs[row * 136 + col];
  }
}

// ---------------- GEMM2: Vpart[tau][n][o][q] = CSA[q] * sum_c U[tau*128+o,c]*NFT[q,c] ----------------
__global__ __launch_bounds__(256) void k_gemmV(const short* __restrict__ Ub,
                                               const short* __restrict__ NFT,
                                               const float* __restrict__ CSAf,
                                               float* __restrict__ Vpart) {
  __shared__ short As[128][40];
  __shared__ short Bs[128][40];
  int tau = blockIdx.x;            // 0..9
  int p0 = blockIdx.y * 128;       // 13 tiles over 1600
  int n = blockIdx.z;
  int tid = threadIdx.x, lane = tid & 63, wave = tid >> 6;
  int quad = lane >> 4, l15 = lane & 15;
  int wm = (wave & 1) * 64, wn = (wave >> 1) * 64;
  int ar = tid >> 2, ko = (tid & 3) * 8;
  const short* Ab = Ub + ((size_t)n * KM + tau * 128) * KC;
  const short* Yb = NFT + (size_t)n * KHW * KC;
  int b0r = min(p0 + ar, KHW - 1), b1r = min(p0 + ar + 64, KHW - 1);
  const short* pa0 = Ab + (size_t)ar * KC + ko;
  const short* pa1 = Ab + (size_t)(ar + 64) * KC + ko;
  const short* pb0 = Yb + (size_t)b0r * KC + ko;
  const short* pb1 = Yb + (size_t)b1r * KC + ko;
  f32x4 acc[4][4] = {};
  for (int k0 = 0; k0 < KC; k0 += 32) {
    __syncthreads();
    *(float4*)&As[ar][ko]      = *(const float4*)&pa0[k0];
    *(float4*)&As[ar + 64][ko] = *(const float4*)&pa1[k0];
    *(float4*)&Bs[ar][ko]      = *(const float4*)&pb0[k0];
    *(float4*)&Bs[ar + 64][ko] = *(const float4*)&pb1[k0];
    __syncthreads();
    short8 a[4], b[4];
    #pragma unroll
    for (int t = 0; t < 4; t++) a[t] = *(const short8*)&As[wm + t * 16 + l15][quad * 8];
    #pragma unroll
    for (int t = 0; t < 4; t++) b[t] = *(const short8*)&Bs[wn + t * 16 + l15][quad * 8];
    #pragma unroll
    for (int ti = 0; ti < 4; ti++)
      #pragma unroll
      for (int tj = 0; tj < 4; tj++)
        acc[ti][tj] = __builtin_amdgcn_mfma_f32_16x16x32_bf16(a[ti], b[tj], acc[ti][tj], 0, 0, 0);
  }
  const float* cs = CSAf + n * KHW;
  float* vb = Vpart + ((size_t)(tau * KN + n)) * KOC * KHW;
  for (int ti = 0; ti < 4; ti++) {
    int o = wm + ti * 16 + quad * 4;
    for (int tj = 0; tj < 4; tj++) {
      int q = p0 + wn + tj * 16 + l15;
      if (q < KHW) {
        float csq = cs[q];
        #pragma unroll
        for (int r = 0; r < 4; r++)
          vb[(size_t)(o + r) * KHW + q] = acc[ti][tj][r] * csq;
      }
    }
  }
}

// h prep: hpadT[n, y+1, x+1, o] = bf16(relu(b1[o] + sum_{tau valid} Vpart[tau][o][p+off]))
__global__ void k_hprep2(const float* __restrict__ Vpart, const float* __restrict__ b1,
                         bf16* __restrict__ hpadT) {
  __shared__ float T[32][132];
  int n = blockIdx.y, p0 = blockIdx.x * 32;
  int tx = threadIdx.x, ty = threadIdx.y;
  int p = p0 + tx;
  int y = p / KH, x = p % KH;
  #pragma unroll
  for (int oc = 0; oc < 16; oc++) {
    int o = oc * 8 + ty;
    float a = b1[o];
    #pragma unroll
    for (int t = 0; t < 9; t++) {
      int dy = t / 3 - 1, dx = t % 3 - 1;
      if ((unsigned)(y + dy) < KH && (unsigned)(x + dx) < KH)
        a += Vpart[((size_t)(t * KN + n) * KOC + o) * KHW + p + dy * KH + dx];
    }
    T[tx][o] = fmaxf(a, 0.0f);
  }
  __syncthreads();
  bf16* hp = hpadT + (size_t)n * KPW * KPW * KOC;
  #pragma unroll
  for (int pc = 0; pc < 4; pc++) {
    int pl = ty * 4 + pc;
    int pp = p0 + pl;
    int yy = pp / KH, xx = pp % KH;
    bf16* row = hp + ((size_t)(yy + 1) * KPW + (xx + 1)) * KOC;
    #pragma unroll
    for (int u = 0; u < 4; u++) row[tx * 4 + u] = __float2bfloat16(T[pl][tx * 4 + u]);
  }
}

// ---------------- conv2 (3x3, 128->128): 128x64 tile, dy-split to dense partials ----------------
__global__ __launch_bounds__(256) void k_conv2(const short* __restrict__ w2p,
                                               const short* __restrict__ hpadT,
                                               float* __restrict__ Cpart) {
  __shared__ short As[128][40];
  __shared__ short Bs[64][40];
  int p0 = blockIdx.x * 64, dy = blockIdx.y, n = blockIdx.z;
  int tid = threadIdx.x, lane = tid & 63, wave = tid >> 6;
  int quad = lane >> 4, l15 = lane & 15;
  int wm = (wave & 1) * 64, wn = (wave >> 1) * 32;
  int ar = tid >> 2, ko = (tid & 3) * 8;
  const short* hb = hpadT + (size_t)n * KPW * KPW * KOC;
  int p = p0 + ar;
  int y0 = p / KH, x0 = p % KH;
  f32x4 acc[4][2] = {};
  for (int dx = 0; dx < 3; ++dx) {
    const short* a0 = w2p + (size_t)ar * 9 * KOC + (dy * 3 + dx) * KOC + ko;
    const short* a1 = w2p + (size_t)(ar + 64) * 9 * KOC + (dy * 3 + dx) * KOC + ko;
    const short* b0 = hb + ((size_t)(y0 + dy) * KPW + (x0 + dx)) * KOC + ko;
    for (int k0 = 0; k0 < KOC; k0 += 32) {
      __syncthreads();
      *(float4*)&As[ar][ko]      = *(const float4*)&a0[k0];
      *(float4*)&As[ar + 64][ko] = *(const float4*)&a1[k0];
      *(float4*)&Bs[ar][ko]      = *(const float4*)&b0[k0];
      __syncthreads();
      short8 a[4], b[2];
      #pragma unroll
      for (int t = 0; t < 4; t++) a[t] = *(const short8*)&As[wm + t * 16 + l15][quad * 8];
      #pragma unroll
      for (int t = 0; t < 2; t++) b[t] = *(const short8*)&Bs[wn + t * 16 + l15][quad * 8];
      #pragma unroll
      for (int ti = 0; ti < 4; ti++)
        #pragma unroll
        for (int tj = 0; tj < 2; tj++)
          acc[ti][tj] = __builtin_amdgcn_mfma_f32_16x16x32_bf16(a[ti], b[tj], acc[ti][tj], 0, 0, 0);
    }
  }
  float* cb = Cpart + ((size_t)(dy * KN + n)) * KOC * KHW;
  for (int ti = 0; ti < 4; ti++) {
    int o = wm + ti * 16 + quad * 4;
    for (int tj = 0; tj < 2; tj++) {
      int q = p0 + wn + tj * 16 + l15;
      #pragma unroll
      for (int r = 0; r < 4; r++)
        cb[(size_t)(o + r) * KHW + q] = acc[ti][tj][r];
    }
  }
}

// out = relu(sum_dy Cpart + b2 + shortcut(Vpart[9]) + bs)
__global__ void k_final2(const float* __restrict__ Cpart, const float* __restrict__ Vpart,
                         const float* __restrict__ b2, const float* __restrict__ bs,
                         float* __restrict__ out) {
  int t = blockIdx.x * 256 + threadIdx.x;
  if (t >= KN * KOC * KHW) return;
  int o = (t / KHW) % KOC;
  const size_t stride = (size_t)KN * KOC * KHW;
  float v = Cpart[t] + Cpart[stride + t] + Cpart[2 * stride + t] +
            Vpart[(size_t)9 * stride + t] + b2[o] + bs[o];
  out[t] = fmaxf(v, 0.0f);
}

// ---------------- launch ----------------
extern "C" void kernel_launch(void* const* d_in, const int* in_sizes, int n_in,
                              void* d_out, int out_size, void* d_ws, size_t ws_size,
                              hipStream_t stream) {
  const float* feats = (const float*)d_in[0];
  const float* sisms = (const float*)d_in[1];
  const float* w1 = (const float*)d_in[2];
  const float* b1 = (const float*)d_in[3];
  const float* w2 = (const float*)d_in[4];
  const float* b2 = (const float*)d_in[5];
  const float* wsc = (const float*)d_in[6];
  const float* bsc = (const float*)d_in[7];
  float* out = (float*)d_out;

  char* w = (char*)d_ws;
  auto carve = [&](size_t bytes) -> void* {
    void* p = (void*)w;
    w += (bytes + 255) & ~(size_t)255;
    return p;
  };
  bf16* NFT   = (bf16*)carve((size_t)KN * KHW * KC * 2);          // 16.4 MB
  bf16* NFcg  = (bf16*)carve((size_t)KN * KC * KHW * 2);          // 16.4 MB
  bf16* Ubuf  = (bf16*)carve((size_t)KN * KM * KC * 2);           // 13.1 MB
  bf16* w1s   = (bf16*)carve((size_t)KM * KHW * 2);               // 4.1 MB
  bf16* hpadT = (bf16*)carve((size_t)KN * KPW * KPW * KOC * 2);   // 4.5 MB
  float* Vpart = (float*)carve((size_t)10 * KN * KOC * KHW * 4);  // 81.9 MB
  float* Cpart = (float*)carve((size_t)3 * KN * KOC * KHW * 4);   // 24.6 MB
  bf16* w2p   = (bf16*)carve((size_t)KOC * 9 * KOC * 2);
  double* psbuf = (double*)carve((size_t)4 * KN * KHW * 8);
  double* rnorm = (double*)carve((size_t)KN * KHW * 8);
  double* vbuf  = (double*)carve((size_t)KN * KC * 8);
  double* SIV   = (double*)carve((size_t)KN * KC * 8);
  double* cm    = (double*)carve((size_t)KN * KN * KHW * 8);
  double* Sbuf  = (double*)carve((size_t)KN * KHW * 8);
  double* tbuf  = (double*)carve((size_t)KN * KN * 8);
  double* wvb   = (double*)carve((size_t)KN * KN * 8);
  double* CSAd  = (double*)carve((size_t)KN * KHW * 8);
  float* CSAf   = (float*)carve((size_t)KN * KHW * 4);
  int* idxb     = (int*)carve((size_t)KN * KHW * 4);

  hipMemsetAsync(hpadT, 0, (size_t)KN * KPW * KPW * KOC * 2, stream);

  k_rnormp<<<dim3(63, 4), 256, 0, stream>>>(feats, psbuf);
  k_rnormc<<<63, 256, 0, stream>>>(psbuf, rnorm);
  k_nft<<<dim3(50, 16, KN), dim3(32, 8), 0, stream>>>(feats, rnorm, NFT);
  k_sivpre<<<KN * KC, 256, 0, stream>>>(feats, sisms, rnorm, vbuf);
  k_sivnorm<<<KN, 512, 0, stream>>>(vbuf, SIV);
  k_cmA<<<dim3(7, KN), 256, 0, stream>>>(feats, rnorm, SIV, cm);
  k_cmnorm<<<KN * KN, 256, 0, stream>>>(cm);
  k_s<<<63, 256, 0, stream>>>(cm, Sbuf);
  k_t<<<KN * KN, 256, 0, stream>>>(cm, Sbuf, tbuf);
  k_wv<<<1, 64, 0, stream>>>(tbuf, wvb);
  k_csa<<<KN, 256, 0, stream>>>(cm, wvb, CSAd, CSAf);
  k_rank<<<dim3(7, KN), 256, 0, stream>>>(CSAd, idxb);

  k_prepw1s<<<KM * KHW / 256, 256, 0, stream>>>(w1, wsc, w1s);
  k_prepw2<<<576, 256, 0, stream>>>(w2, w2p);
  k_gath2<<<dim3(50, 16, KN), dim3(32, 8), 0, stream>>>((const short*)NFT, idxb, (short*)NFcg);

  k_gemmU<<<dim3(10, 4, KN), 256, 0, stream>>>((const short*)w1s, (const short*)NFcg, Ubuf);
  k_gemmV<<<dim3(10, 13, KN), 256, 0, stream>>>((const short*)Ubuf, (const short*)NFT,
                                                CSAf, Vpart);
  k_hprep2<<<dim3(50, KN), dim3(32, 8), 0, stream>>>(Vpart, b1, hpadT);
  k_conv2<<<dim3(25, 3, KN), 256, 0, stream>>>((const short*)w2p, (const short*)hpadT, Cpart);
  k_final2<<<8000, 256, 0, stream>>>(Cpart, Vpart, b2, bsc, out);
}

// Round 8
// 396.817 us; speedup vs baseline: 1.1268x; 1.1268x over previous
//
#include <hip/hip_runtime.h>
#include <hip/hip_bf16.h>
#include <math.h>

typedef short short8 __attribute__((ext_vector_type(8)));
typedef float f32x4 __attribute__((ext_vector_type(4)));
typedef __hip_bfloat16 bf16;

// problem constants
#define KN 10
#define KC 512
#define KHW 1600
#define KH 40
#define KOC 128
#define KPW 42   // padded spatial (40+2)
#define KM 1280  // stacked M: 9 conv taps * 128 + 128 shortcut

// ---------------- block reduction helpers (fp64) ----------------
__device__ __forceinline__ double blockReduceSumD(double v) {
  __shared__ double tmpS[8];
  int lane = threadIdx.x & 63, wv = threadIdx.x >> 6;
  #pragma unroll
  for (int o = 32; o > 0; o >>= 1) v += __shfl_down(v, o);
  if (lane == 0) tmpS[wv] = v;
  __syncthreads();
  if (threadIdx.x == 0) {
    int nw = (blockDim.x + 63) >> 6;
    double s = 0;
    for (int i = 0; i < nw; i++) s += tmpS[i];
    tmpS[0] = s;
  }
  __syncthreads();
  double r = tmpS[0];
  __syncthreads();
  return r;
}

__device__ __forceinline__ double blockReduceMinD(double v) {
  __shared__ double tmpMn[8];
  int lane = threadIdx.x & 63, wv = threadIdx.x >> 6;
  #pragma unroll
  for (int o = 32; o > 0; o >>= 1) v = fmin(v, __shfl_down(v, o));
  if (lane == 0) tmpMn[wv] = v;
  __syncthreads();
  if (threadIdx.x == 0) {
    int nw = (blockDim.x + 63) >> 6;
    double s = tmpMn[0];
    for (int i = 1; i < nw; i++) s = fmin(s, tmpMn[i]);
    tmpMn[0] = s;
  }
  __syncthreads();
  double r = tmpMn[0];
  __syncthreads();
  return r;
}

__device__ __forceinline__ double blockReduceMaxD(double v) {
  __shared__ double tmpMx[8];
  int lane = threadIdx.x & 63, wv = threadIdx.x >> 6;
  #pragma unroll
  for (int o = 32; o > 0; o >>= 1) v = fmax(v, __shfl_down(v, o));
  if (lane == 0) tmpMx[wv] = v;
  __syncthreads();
  if (threadIdx.x == 0) {
    int nw = (blockDim.x + 63) >> 6;
    double s = tmpMx[0];
    for (int i = 1; i < nw; i++) s = fmax(s, tmpMx[i]);
    tmpMx[0] = s;
  }
  __syncthreads();
  double r = tmpMx[0];
  __syncthreads();
  return r;
}

// ---------------- small chain (fp64 for argsort stability) ----------------

// phase 1: partial sum of squares over a c-chunk
__global__ void k_rnormp(const float* __restrict__ feats, double* __restrict__ ps) {
  int t = blockIdx.x * 256 + threadIdx.x;
  if (t >= KN * KHW) return;
  int ci = blockIdx.y;
  int n = t / KHW, k = t % KHW;
  const float* p = feats + (size_t)n * KC * KHW + (size_t)ci * 128 * KHW + k;
  double s = 0.0;
  for (int c = 0; c < 128; ++c) { double v = p[(size_t)c * KHW]; s += v * v; }
  ps[(size_t)ci * KN * KHW + t] = s;
}

// phase 2: combine 4 partials -> rnorm
__global__ void k_rnormc(const double* __restrict__ ps, double* __restrict__ rnorm) {
  int t = blockIdx.x * 256 + threadIdx.x;
  if (t >= KN * KHW) return;
  double s = ps[t] + ps[KN * KHW + t] + ps[2 * KN * KHW + t] + ps[3 * KN * KHW + t];
  double nn = sqrt(s);
  if (nn < 1e-12) nn = 1e-12;
  rnorm[t] = 1.0 / nn;
}

// NFT[n,k,c] = bf16(feats[n,c,k] * rnorm[n,k]); also emits SIV pre-partials
// vpp[n][c][kchunk] = sum_{k in chunk} feats[n,c,k]*rnorm[n,k]*sism[n,k]
__global__ void k_nft(const float* __restrict__ feats, const double* __restrict__ rnorm,
                      const float* __restrict__ sism, bf16* __restrict__ NFT,
                      double* __restrict__ vpp) {
  __shared__ float T[32][33];
  int n = blockIdx.z, k0 = blockIdx.x * 32, c0 = blockIdx.y * 32;
  int tx = threadIdx.x, ty = threadIdx.y;
  const float* fb = feats + ((size_t)n * KC + c0) * KHW + k0;
  #pragma unroll
  for (int ii = 0; ii < 4; ii++) {
    int cl = ty * 4 + ii;
    T[cl][tx] = fb[(size_t)cl * KHW + tx];
  }
  __syncthreads();
  bf16* ob = NFT + ((size_t)n * KHW + k0) * KC + c0;
  #pragma unroll
  for (int ii = 0; ii < 4; ii++) {
    int kl = ty * 4 + ii;
    float r = (float)rnorm[n * KHW + k0 + kl];
    ob[(size_t)kl * KC + tx] = __float2bfloat16(T[tx][kl] * r);
  }
  // SIV partial: reduce over the 32 k of this tile (32-wide shuffle within ty group)
  double rs = rnorm[n * KHW + k0 + tx] * (double)sism[n * KHW + k0 + tx];
  #pragma unroll
  for (int ii = 0; ii < 4; ii++) {
    int cl = ty * 4 + ii;
    double v = (double)T[cl][tx] * rs;
    #pragma unroll
    for (int o = 16; o > 0; o >>= 1) v += __shfl_down(v, o, 32);
    if (tx == 0) vpp[((size_t)n * KC + c0 + cl) * 50 + k0 / 32] = v;
  }
}

// combine 50 partials -> mean -> l2 normalize -> SIV[n,c]
__global__ void k_sivnorm2(const double* __restrict__ vpp, double* __restrict__ SIV) {
  int n = blockIdx.x, c = threadIdx.x;   // 512 threads
  const double* p = vpp + ((size_t)n * KC + c) * 50;
  double acc = 0;
  #pragma unroll 5
  for (int j = 0; j < 50; j++) acc += p[j];
  acc /= (double)KHW;
  double s2 = blockReduceSumD(acc * acc);
  double nn = sqrt(s2);
  if (nn < 1e-12) nn = 1e-12;
  SIV[n * KC + c] = acc / nn;
}

// cm partial over c-chunk: cmp[ci][n][m][k] = sum_{c in chunk} feats[n,c,k]*SIV[m,c]
__global__ void k_cmP(const float* __restrict__ feats, const double* __restrict__ SIV,
                      double* __restrict__ cmp) {
  __shared__ double sv[KN][64];
  int kc = blockIdx.x, ci = blockIdx.y, n = blockIdx.z;
  for (int t = threadIdx.x; t < KN * 64; t += 256) {
    int m = t / 64, c = t % 64;
    sv[m][c] = SIV[m * KC + ci * 64 + c];
  }
  __syncthreads();
  int k = kc * 256 + threadIdx.x;
  if (k >= KHW) return;
  const float* f = feats + ((size_t)n * KC + ci * 64) * KHW + k;
  double acc[KN];
  #pragma unroll
  for (int m = 0; m < KN; m++) acc[m] = 0.0;
  for (int c = 0; c < 64; ++c) {
    double fv = f[(size_t)c * KHW];
    #pragma unroll
    for (int m = 0; m < KN; m++) acc[m] += fv * sv[m][c];
  }
  const size_t str = (size_t)KN * KN * KHW;
  #pragma unroll
  for (int m = 0; m < KN; m++)
    cmp[(size_t)ci * str + ((size_t)n * KN + m) * KHW + k] = acc[m];
}

// combine 8 c-partials, scale by rnorm -> cm[n,m,k]
__global__ void k_cmB(const double* __restrict__ cmp, const double* __restrict__ rnorm,
                      double* __restrict__ cm) {
  size_t t = (size_t)blockIdx.x * 256 + threadIdx.x;
  if (t >= (size_t)KN * KN * KHW) return;
  int k = t % KHW;
  int n = (int)(t / ((size_t)KN * KHW));
  const size_t str = (size_t)KN * KN * KHW;
  double s = 0;
  #pragma unroll
  for (int ci = 0; ci < 8; ci++) s += cmp[ci * str + t];
  cm[t] = s * rnorm[n * KHW + k];
}

__global__ void k_cmnorm(double* __restrict__ cm) {
  double* row = cm + (size_t)blockIdx.x * KHW;
  double s = 0;
  for (int k = threadIdx.x; k < KHW; k += 256) { double v = row[k]; s += v * v; }
  s = blockReduceSumD(s);
  double nn = sqrt(s);
  if (nn < 1e-12) nn = 1e-12;
  double rn = 1.0 / nn;
  for (int k = threadIdx.x; k < KHW; k += 256) row[k] *= rn;
}

// t[n,m] = sum_k cm[n,m,k] * S[n,k], S computed on the fly (same order as before)
__global__ void k_st(const double* __restrict__ cm, double* __restrict__ tbuf) {
  int b = blockIdx.x;
  int n = b / KN, m = b % KN;
  const double* base = cm + (size_t)n * KN * KHW;
  double acc = 0;
  for (int k = threadIdx.x; k < KHW; k += 256) {
    double S = 0;
    #pragma unroll
    for (int mm = 0; mm < KN; mm++) S += base[(size_t)mm * KHW + k];
    acc += base[(size_t)m * KHW + k] * S;
  }
  acc = blockReduceSumD(acc);
  if (threadIdx.x == 0) tbuf[b] = acc;
}

// CSA: softmax(tbuf[n,:]) folded in (thread 0), then weighted sum + min-max
__global__ void k_csa(const double* __restrict__ cm, const double* __restrict__ tbuf,
                      double* __restrict__ CSAd, float* __restrict__ CSAf) {
  __shared__ double w[KN];
  int n = blockIdx.x, tid = threadIdx.x;
  if (tid == 0) {
    double v[KN], mx = -1e300;
    #pragma unroll
    for (int m = 0; m < KN; m++) { v[m] = tbuf[n * KN + m]; mx = fmax(mx, v[m]); }
    double s = 0;
    #pragma unroll
    for (int m = 0; m < KN; m++) { v[m] = exp(v[m] - mx); s += v[m]; }
    #pragma unroll
    for (int m = 0; m < KN; m++) w[m] = v[m] / s;
  }
  __syncthreads();
  double v[7];
  int cnt = 0;
  double lmin = 1e300, lmax = -1e300;
  for (int k = tid; k < KHW; k += 256) {
    double a = 0;
    #pragma unroll
    for (int m = 0; m < KN; m++) a += cm[((size_t)n * KN + m) * KHW + k] * w[m];
    v[cnt++] = a;
    lmin = fmin(lmin, a);
    lmax = fmax(lmax, a);
  }
  double mn = blockReduceMinD(lmin);
  double mx = blockReduceMaxD(lmax);
  double inv = 1.0 / (mx - mn + 1e-12);
  cnt = 0;
  for (int k = tid; k < KHW; k += 256) {
    double nv = (v[cnt++] - mn) * inv;
    CSAd[(size_t)n * KHW + k] = nv;
    CSAf[(size_t)n * KHW + k] = (float)nv;
  }
}

// rank-based stable descending argsort: idx[rank[i]] = i
__global__ void k_rank(const double* __restrict__ CSAd, int* __restrict__ idx) {
  __shared__ double key[KHW];
  int n = blockIdx.y;
  for (int i = threadIdx.x; i < KHW; i += 256) key[i] = CSAd[(size_t)n * KHW + i];
  __syncthreads();
  int i = blockIdx.x * 256 + threadIdx.x;
  if (i >= KHW) return;
  double ki = key[i];
  int r = 0;
  #pragma unroll 4
  for (int j = 0; j < KHW; j++) {
    double kj = key[j];
    r += (kj > ki) || (kj == ki && j < i);
  }
  idx[n * KHW + r] = i;
}

// ---------------- stacked weights (n-independent): w1s[(tau,o)][i] ----------------
__global__ void k_prepw1s(const float* __restrict__ w1, const float* __restrict__ wsc,
                          bf16* __restrict__ w1s) {
  int t = blockIdx.x * 256 + threadIdx.x;   // over KM*KHW
  int m = t / KHW, i = t % KHW;
  int tau = m >> 7, o = m & 127;
  float v = (tau < 9) ? w1[((size_t)o * KHW + i) * 9 + tau]
                      : wsc[(size_t)o * KHW + i];
  w1s[t] = __float2bfloat16(v);
}

__global__ void k_prepw2(const float* __restrict__ w2, bf16* __restrict__ w2p) {
  int t = blockIdx.x * 256 + threadIdx.x;
  if (t >= KOC * 9 * KOC) return;
  int o = t / (9 * KOC), r = t % (9 * KOC);
  int s = r / KOC, i = r % KOC;
  w2p[t] = __float2bfloat16(w2[(size_t)o * 9 * KOC + (size_t)i * 9 + s]);
}

// ---------------- NF column gather from NFT rows: NFcg[n][c][i] = NFT[n][idx[i]][c] ----------------
__global__ void k_gath2(const short* __restrict__ NFT, const int* __restrict__ idx,
                        short* __restrict__ NFcg) {
  __shared__ short T[32][33];
  int i0 = blockIdx.x * 32, c0 = blockIdx.y * 32, n = blockIdx.z;
  int tx = threadIdx.x, ty = threadIdx.y;
  #pragma unroll
  for (int ii = 0; ii < 4; ii++) {
    int row = ty * 4 + ii;
    int id = idx[n * KHW + i0 + row];
    T[row][tx] = NFT[((size_t)n * KHW + id) * KC + c0 + tx];
  }
  __syncthreads();
  #pragma unroll
  for (int ii = 0; ii < 4; ii++) {
    int cl = ty * 4 + ii;
    NFcg[((size_t)n * KC + c0 + cl) * KHW + i0 + tx] = T[tx][cl];
  }
}

// ---------------- GEMM1: U[n][m][c] = sum_i w1s[m,i] * NFcg[n,c,i] ----------------
__global__ __launch_bounds__(256) void k_gemmU(const short* __restrict__ w1s,
                                               const short* __restrict__ NFcg,
                                               bf16* __restrict__ U) {
  __shared__ short smem[128 * 136];          // aliased As/Bs then Cs
  short* As = smem;                          // [128][40]
  short* Bs = smem + 128 * 40;               // [128][40]
  short* Cs = smem;                          // [128][136]
  int n = blockIdx.z;
  int m0 = blockIdx.x * 128, c0 = blockIdx.y * 128;
  int tid = threadIdx.x, lane = tid & 63, wave = tid >> 6;
  int quad = lane >> 4, l15 = lane & 15;
  int wm = (wave & 1) * 64, wn = (wave >> 1) * 64;
  int ar = tid >> 2, ko = (tid & 3) * 8;
  const short* Bb = NFcg + (size_t)n * KC * KHW;
  const short* pa0 = w1s + (size_t)(m0 + ar) * KHW + ko;
  const short* pa1 = w1s + (size_t)(m0 + ar + 64) * KHW + ko;
  const short* pb0 = Bb + (size_t)(c0 + ar) * KHW + ko;
  const short* pb1 = Bb + (size_t)(c0 + ar + 64) * KHW + ko;
  f32x4 acc[4][4] = {};
  for (int k0 = 0; k0 < KHW; k0 += 32) {
    __syncthreads();
    *(float4*)&As[ar * 40 + ko]        = *(const float4*)&pa0[k0];
    *(float4*)&As[(ar + 64) * 40 + ko] = *(const float4*)&pa1[k0];
    *(float4*)&Bs[ar * 40 + ko]        = *(const float4*)&pb0[k0];
    *(float4*)&Bs[(ar + 64) * 40 + ko] = *(const float4*)&pb1[k0];
    __syncthreads();
    short8 a[4], b[4];
    #pragma unroll
    for (int t = 0; t < 4; t++) a[t] = *(const short8*)&As[(wm + t * 16 + l15) * 40 + quad * 8];
    #pragma unroll
    for (int t = 0; t < 4; t++) b[t] = *(const short8*)&Bs[(wn + t * 16 + l15) * 40 + quad * 8];
    #pragma unroll
    for (int ti = 0; ti < 4; ti++)
      #pragma unroll
      for (int tj = 0; tj < 4; tj++)
        acc[ti][tj] = __builtin_amdgcn_mfma_f32_16x16x32_bf16(a[ti], b[tj], acc[ti][tj], 0, 0, 0);
  }
  __syncthreads();   // frag reads done; reuse smem as Cs
  #pragma unroll
  for (int ti = 0; ti < 4; ti++) {
    int lr = wm + ti * 16 + quad * 4;
    #pragma unroll
    for (int tj = 0; tj < 4; tj++) {
      int lc = wn + tj * 16 + l15;
      #pragma unroll
      for (int r = 0; r < 4; r++)
        *(bf16*)&Cs[(lr + r) * 136 + lc] = __float2bfloat16(acc[ti][tj][r]);
    }
  }
  __syncthreads();
  #pragma unroll
  for (int pass = 0; pass < 8; pass++) {
    int row = pass * 16 + (tid >> 4);
    int col = (tid & 15) * 8;
    *(float4*)&U[((size_t)n * KM + m0 + row) * KC + c0 + col] =
        *(const float4*)&Cs[row * 136 + col];
  }
}

// ---------------- GEMM2: Vpart[tau][n][o][q] = CSA[q] * sum_c U[tau*128+o,c]*NFT[q,c] ----------------
__global__ __launch_bounds__(256) void k_gemmV(const short* __restrict__ Ub,
                                               const short* __restrict__ NFT,
                                               const float* __restrict__ CSAf,
                                               float* __restrict__ Vpart) {
  __shared__ short As[128][40];
  __shared__ short Bs[128][40];
  int tau = blockIdx.x;            // 0..9
  int p0 = blockIdx.y * 128;       // 13 tiles over 1600
  int n = blockIdx.z;
  int tid = threadIdx.x, lane = tid & 63, wave = tid >> 6;
  int quad = lane >> 4, l15 = lane & 15;
  int wm = (wave & 1) * 64, wn = (wave >> 1) * 64;
  int ar = tid >> 2, ko = (tid & 3) * 8;
  const short* Ab = Ub + ((size_t)n * KM + tau * 128) * KC;
  const short* Yb = NFT + (size_t)n * KHW * KC;
  int b0r = min(p0 + ar, KHW - 1), b1r = min(p0 + ar + 64, KHW - 1);
  const short* pa0 = Ab + (size_t)ar * KC + ko;
  const short* pa1 = Ab + (size_t)(ar + 64) * KC + ko;
  const short* pb0 = Yb + (size_t)b0r * KC + ko;
  const short* pb1 = Yb + (size_t)b1r * KC + ko;
  f32x4 acc[4][4] = {};
  for (int k0 = 0; k0 < KC; k0 += 32) {
    __syncthreads();
    *(float4*)&As[ar][ko]      = *(const float4*)&pa0[k0];
    *(float4*)&As[ar + 64][ko] = *(const float4*)&pa1[k0];
    *(float4*)&Bs[ar][ko]      = *(const float4*)&pb0[k0];
    *(float4*)&Bs[ar + 64][ko] = *(const float4*)&pb1[k0];
    __syncthreads();
    short8 a[4], b[4];
    #pragma unroll
    for (int t = 0; t < 4; t++) a[t] = *(const short8*)&As[wm + t * 16 + l15][quad * 8];
    #pragma unroll
    for (int t = 0; t < 4; t++) b[t] = *(const short8*)&Bs[wn + t * 16 + l15][quad * 8];
    #pragma unroll
    for (int ti = 0; ti < 4; ti++)
      #pragma unroll
      for (int tj = 0; tj < 4; tj++)
        acc[ti][tj] = __builtin_amdgcn_mfma_f32_16x16x32_bf16(a[ti], b[tj], acc[ti][tj], 0, 0, 0);
  }
  const float* cs = CSAf + n * KHW;
  float* vb = Vpart + ((size_t)(tau * KN + n)) * KOC * KHW;
  for (int ti = 0; ti < 4; ti++) {
    int o = wm + ti * 16 + quad * 4;
    for (int tj = 0; tj < 4; tj++) {
      int q = p0 + wn + tj * 16 + l15;
      if (q < KHW) {
        float csq = cs[q];
        #pragma unroll
        for (int r = 0; r < 4; r++)
          vb[(size_t)(o + r) * KHW + q] = acc[ti][tj][r] * csq;
      }
    }
  }
}

// h prep: hpadT[n, y+1, x+1, o] = bf16(relu(b1[o] + sum_{tau valid} Vpart[tau][o][p+off]))
__global__ void k_hprep2(const float* __restrict__ Vpart, const float* __restrict__ b1,
                         bf16* __restrict__ hpadT) {
  __shared__ float T[32][132];
  int n = blockIdx.y, p0 = blockIdx.x * 32;
  int tx = threadIdx.x, ty = threadIdx.y;
  int p = p0 + tx;
  int y = p / KH, x = p % KH;
  #pragma unroll
  for (int oc = 0; oc < 16; oc++) {
    int o = oc * 8 + ty;
    float a = b1[o];
    #pragma unroll
    for (int t = 0; t < 9; t++) {
      int dy = t / 3 - 1, dx = t % 3 - 1;
      if ((unsigned)(y + dy) < KH && (unsigned)(x + dx) < KH)
        a += Vpart[((size_t)(t * KN + n) * KOC + o) * KHW + p + dy * KH + dx];
    }
    T[tx][o] = fmaxf(a, 0.0f);
  }
  __syncthreads();
  bf16* hp = hpadT + (size_t)n * KPW * KPW * KOC;
  #pragma unroll
  for (int pc = 0; pc < 4; pc++) {
    int pl = ty * 4 + pc;
    int pp = p0 + pl;
    int yy = pp / KH, xx = pp % KH;
    bf16* row = hp + ((size_t)(yy + 1) * KPW + (xx + 1)) * KOC;
    #pragma unroll
    for (int u = 0; u < 4; u++) row[tx * 4 + u] = __float2bfloat16(T[pl][tx * 4 + u]);
  }
}

// ---------------- conv2 (3x3, 128->128): 128x64 tile, dy-split to dense partials ----------------
__global__ __launch_bounds__(256) void k_conv2(const short* __restrict__ w2p,
                                               const short* __restrict__ hpadT,
                                               float* __restrict__ Cpart) {
  __shared__ short As[128][40];
  __shared__ short Bs[64][40];
  int p0 = blockIdx.x * 64, dy = blockIdx.y, n = blockIdx.z;
  int tid = threadIdx.x, lane = tid & 63, wave = tid >> 6;
  int quad = lane >> 4, l15 = lane & 15;
  int wm = (wave & 1) * 64, wn = (wave >> 1) * 32;
  int ar = tid >> 2, ko = (tid & 3) * 8;
  const short* hb = hpadT + (size_t)n * KPW * KPW * KOC;
  int p = p0 + ar;
  int y0 = p / KH, x0 = p % KH;
  f32x4 acc[4][2] = {};
  for (int dx = 0; dx < 3; ++dx) {
    const short* a0 = w2p + (size_t)ar * 9 * KOC + (dy * 3 + dx) * KOC + ko;
    const short* a1 = w2p + (size_t)(ar + 64) * 9 * KOC + (dy * 3 + dx) * KOC + ko;
    const short* b0 = hb + ((size_t)(y0 + dy) * KPW + (x0 + dx)) * KOC + ko;
    for (int k0 = 0; k0 < KOC; k0 += 32) {
      __syncthreads();
      *(float4*)&As[ar][ko]      = *(const float4*)&a0[k0];
      *(float4*)&As[ar + 64][ko] = *(const float4*)&a1[k0];
      *(float4*)&Bs[ar][ko]      = *(const float4*)&b0[k0];
      __syncthreads();
      short8 a[4], b[2];
      #pragma unroll
      for (int t = 0; t < 4; t++) a[t] = *(const short8*)&As[wm + t * 16 + l15][quad * 8];
      #pragma unroll
      for (int t = 0; t < 2; t++) b[t] = *(const short8*)&Bs[wn + t * 16 + l15][quad * 8];
      #pragma unroll
      for (int ti = 0; ti < 4; ti++)
        #pragma unroll
        for (int tj = 0; tj < 2; tj++)
          acc[ti][tj] = __builtin_amdgcn_mfma_f32_16x16x32_bf16(a[ti], b[tj], acc[ti][tj], 0, 0, 0);
    }
  }
  float* cb = Cpart + ((size_t)(dy * KN + n)) * KOC * KHW;
  for (int ti = 0; ti < 4; ti++) {
    int o = wm + ti * 16 + quad * 4;
    for (int tj = 0; tj < 2; tj++) {
      int q = p0 + wn + tj * 16 + l15;
      #pragma unroll
      for (int r = 0; r < 4; r++)
        cb[(size_t)(o + r) * KHW + q] = acc[ti][tj][r];
    }
  }
}

// out = relu(sum_dy Cpart + b2 + shortcut(Vpart[9]) + bs)
__global__ void k_final2(const float* __restrict__ Cpart, const float* __restrict__ Vpart,
                         const float* __restrict__ b2, const float* __restrict__ bs,
                         float* __restrict__ out) {
  int t = blockIdx.x * 256 + threadIdx.x;
  if (t >= KN * KOC * KHW) return;
  int o = (t / KHW) % KOC;
  const size_t stride = (size_t)KN * KOC * KHW;
  float v = Cpart[t] + Cpart[stride + t] + Cpart[2 * stride + t] +
            Vpart[(size_t)9 * stride + t] + b2[o] + bs[o];
  out[t] = fmaxf(v, 0.0f);
}

// ---------------- launch ----------------
extern "C" void kernel_launch(void* const* d_in, const int* in_sizes, int n_in,
                              void* d_out, int out_size, void* d_ws, size_t ws_size,
                              hipStream_t stream) {
  const float* feats = (const float*)d_in[0];
  const float* sisms = (const float*)d_in[1];
  const float* w1 = (const float*)d_in[2];
  const float* b1 = (const float*)d_in[3];
  const float* w2 = (const float*)d_in[4];
  const float* b2 = (const float*)d_in[5];
  const float* wsc = (const float*)d_in[6];
  const float* bsc = (const float*)d_in[7];
  float* out = (float*)d_out;

  char* w = (char*)d_ws;
  auto carve = [&](size_t bytes) -> void* {
    void* p = (void*)w;
    w += (bytes + 255) & ~(size_t)255;
    return p;
  };
  bf16* NFT   = (bf16*)carve((size_t)KN * KHW * KC * 2);          // 16.4 MB
  bf16* NFcg  = (bf16*)carve((size_t)KN * KC * KHW * 2);          // 16.4 MB
  bf16* Ubuf  = (bf16*)carve((size_t)KN * KM * KC * 2);           // 13.1 MB
  bf16* w1s   = (bf16*)carve((size_t)KM * KHW * 2);               // 4.1 MB
  bf16* hpadT = (bf16*)carve((size_t)KN * KPW * KPW * KOC * 2);   // 4.5 MB
  float* Vpart = (float*)carve((size_t)10 * KN * KOC * KHW * 4);  // 81.9 MB
  float* Cpart = (float*)carve((size_t)3 * KN * KOC * KHW * 4);   // 24.6 MB
  bf16* w2p   = (bf16*)carve((size_t)KOC * 9 * KOC * 2);
  double* psbuf = (double*)carve((size_t)4 * KN * KHW * 8);
  double* rnorm = (double*)carve((size_t)KN * KHW * 8);
  double* vpp   = (double*)carve((size_t)KN * KC * 50 * 8);       // 2.05 MB
  double* SIV   = (double*)carve((size_t)KN * KC * 8);
  double* cmp   = (double*)carve((size_t)8 * KN * KN * KHW * 8);  // 10.2 MB
  double* cm    = (double*)carve((size_t)KN * KN * KHW * 8);
  double* tbuf  = (double*)carve((size_t)KN * KN * 8);
  double* CSAd  = (double*)carve((size_t)KN * KHW * 8);
  float* CSAf   = (float*)carve((size_t)KN * KHW * 4);
  int* idxb     = (int*)carve((size_t)KN * KHW * 4);

  hipMemsetAsync(hpadT, 0, (size_t)KN * KPW * KPW * KOC * 2, stream);

  k_rnormp<<<dim3(63, 4), 256, 0, stream>>>(feats, psbuf);
  k_rnormc<<<63, 256, 0, stream>>>(psbuf, rnorm);
  k_nft<<<dim3(50, 16, KN), dim3(32, 8), 0, stream>>>(feats, rnorm, sisms, NFT, vpp);
  k_sivnorm2<<<KN, 512, 0, stream>>>(vpp, SIV);
  k_cmP<<<dim3(7, 8, KN), 256, 0, stream>>>(feats, SIV, cmp);
  k_cmB<<<625, 256, 0, stream>>>(cmp, rnorm, cm);
  k_cmnorm<<<KN * KN, 256, 0, stream>>>(cm);
  k_st<<<KN * KN, 256, 0, stream>>>(cm, tbuf);
  k_csa<<<KN, 256, 0, stream>>>(cm, tbuf, CSAd, CSAf);
  k_rank<<<dim3(7, KN), 256, 0, stream>>>(CSAd, idxb);

  k_prepw1s<<<KM * KHW / 256, 256, 0, stream>>>(w1, wsc, w1s);
  k_prepw2<<<576, 256, 0, stream>>>(w2, w2p);
  k_gath2<<<dim3(50, 16, KN), dim3(32, 8), 0, stream>>>((const short*)NFT, idxb, (short*)NFcg);

  k_gemmU<<<dim3(10, 4, KN), 256, 0, stream>>>((const short*)w1s, (const short*)NFcg, Ubuf);
  k_gemmV<<<dim3(10, 13, KN), 256, 0, stream>>>((const short*)Ubuf, (const short*)NFT,
                                                CSAf, Vpart);
  k_hprep2<<<dim3(50, KN), dim3(32, 8), 0, stream>>>(Vpart, b1, hpadT);
  k_conv2<<<dim3(25, 3, KN), 256, 0, stream>>>((const short*)w2p, (const short*)hpadT, Cpart);
  k_final2<<<8000, 256, 0, stream>>>(Cpart, Vpart, b2, bsc, out);
}

// Round 9
// 370.051 us; speedup vs baseline: 1.2083x; 1.0723x over previous
//
#include <hip/hip_runtime.h>
#include <hip/hip_bf16.h>
#include <math.h>

typedef short short8 __attribute__((ext_vector_type(8)));
typedef short short4v __attribute__((ext_vector_type(4)));
typedef float f32x4 __attribute__((ext_vector_type(4)));
typedef __hip_bfloat16 bf16;

// problem constants
#define KN 10
#define KC 512
#define KHW 1600
#define KH 40
#define KOC 128
#define KPW 42   // padded spatial (40+2)
#define KM 1280  // stacked M: 9 conv taps * 128 + 128 shortcut

// ---------------- block reduction helpers (fp64) ----------------
__device__ __forceinline__ double blockReduceSumD(double v) {
  __shared__ double tmpS[8];
  int lane = threadIdx.x & 63, wv = threadIdx.x >> 6;
  #pragma unroll
  for (int o = 32; o > 0; o >>= 1) v += __shfl_down(v, o);
  if (lane == 0) tmpS[wv] = v;
  __syncthreads();
  if (threadIdx.x == 0) {
    int nw = (blockDim.x + 63) >> 6;
    double s = 0;
    for (int i = 0; i < nw; i++) s += tmpS[i];
    tmpS[0] = s;
  }
  __syncthreads();
  double r = tmpS[0];
  __syncthreads();
  return r;
}

__device__ __forceinline__ double blockReduceMinD(double v) {
  __shared__ double tmpMn[8];
  int lane = threadIdx.x & 63, wv = threadIdx.x >> 6;
  #pragma unroll
  for (int o = 32; o > 0; o >>= 1) v = fmin(v, __shfl_down(v, o));
  if (lane == 0) tmpMn[wv] = v;
  __syncthreads();
  if (threadIdx.x == 0) {
    int nw = (blockDim.x + 63) >> 6;
    double s = tmpMn[0];
    for (int i = 1; i < nw; i++) s = fmin(s, tmpMn[i]);
    tmpMn[0] = s;
  }
  __syncthreads();
  double r = tmpMn[0];
  __syncthreads();
  return r;
}

__device__ __forceinline__ double blockReduceMaxD(double v) {
  __shared__ double tmpMx[8];
  int lane = threadIdx.x & 63, wv = threadIdx.x >> 6;
  #pragma unroll
  for (int o = 32; o > 0; o >>= 1) v = fmax(v, __shfl_down(v, o));
  if (lane == 0) tmpMx[wv] = v;
  __syncthreads();
  if (threadIdx.x == 0) {
    int nw = (blockDim.x + 63) >> 6;
    double s = tmpMx[0];
    for (int i = 1; i < nw; i++) s = fmax(s, tmpMx[i]);
    tmpMx[0] = s;
  }
  __syncthreads();
  double r = tmpMx[0];
  __syncthreads();
  return r;
}

// ---------------- small chain (fp64 for argsort stability) ----------------

__global__ void k_rnormp(const float* __restrict__ feats, double* __restrict__ ps) {
  int t = blockIdx.x * 256 + threadIdx.x;
  if (t >= KN * KHW) return;
  int ci = blockIdx.y;
  int n = t / KHW, k = t % KHW;
  const float* p = feats + (size_t)n * KC * KHW + (size_t)ci * 128 * KHW + k;
  double s = 0.0;
  for (int c = 0; c < 128; ++c) { double v = p[(size_t)c * KHW]; s += v * v; }
  ps[(size_t)ci * KN * KHW + t] = s;
}

__global__ void k_rnormc(const double* __restrict__ ps, double* __restrict__ rnorm) {
  int t = blockIdx.x * 256 + threadIdx.x;
  if (t >= KN * KHW) return;
  double s = ps[t] + ps[KN * KHW + t] + ps[2 * KN * KHW + t] + ps[3 * KN * KHW + t];
  double nn = sqrt(s);
  if (nn < 1e-12) nn = 1e-12;
  rnorm[t] = 1.0 / nn;
}

// NFT[n,k,c] = bf16(feats[n,c,k] * rnorm[n,k]); also emits SIV pre-partials
__global__ void k_nft(const float* __restrict__ feats, const double* __restrict__ rnorm,
                      const float* __restrict__ sism, bf16* __restrict__ NFT,
                      double* __restrict__ vpp) {
  __shared__ float T[32][33];
  int n = blockIdx.z, k0 = blockIdx.x * 32, c0 = blockIdx.y * 32;
  int tx = threadIdx.x, ty = threadIdx.y;
  const float* fb = feats + ((size_t)n * KC + c0) * KHW + k0;
  #pragma unroll
  for (int ii = 0; ii < 4; ii++) {
    int cl = ty * 4 + ii;
    T[cl][tx] = fb[(size_t)cl * KHW + tx];
  }
  __syncthreads();
  bf16* ob = NFT + ((size_t)n * KHW + k0) * KC + c0;
  #pragma unroll
  for (int ii = 0; ii < 4; ii++) {
    int kl = ty * 4 + ii;
    float r = (float)rnorm[n * KHW + k0 + kl];
    ob[(size_t)kl * KC + tx] = __float2bfloat16(T[tx][kl] * r);
  }
  double rs = rnorm[n * KHW + k0 + tx] * (double)sism[n * KHW + k0 + tx];
  #pragma unroll
  for (int ii = 0; ii < 4; ii++) {
    int cl = ty * 4 + ii;
    double v = (double)T[cl][tx] * rs;
    #pragma unroll
    for (int o = 16; o > 0; o >>= 1) v += __shfl_down(v, o, 32);
    if (tx == 0) vpp[((size_t)n * KC + c0 + cl) * 50 + k0 / 32] = v;
  }
}

__global__ void k_sivnorm2(const double* __restrict__ vpp, double* __restrict__ SIV) {
  int n = blockIdx.x, c = threadIdx.x;   // 512 threads
  const double* p = vpp + ((size_t)n * KC + c) * 50;
  double acc = 0;
  #pragma unroll 5
  for (int j = 0; j < 50; j++) acc += p[j];
  acc /= (double)KHW;
  double s2 = blockReduceSumD(acc * acc);
  double nn = sqrt(s2);
  if (nn < 1e-12) nn = 1e-12;
  SIV[n * KC + c] = acc / nn;
}

__global__ void k_cmP(const float* __restrict__ feats, const double* __restrict__ SIV,
                      double* __restrict__ cmp) {
  __shared__ double sv[KN][64];
  int kc = blockIdx.x, ci = blockIdx.y, n = blockIdx.z;
  for (int t = threadIdx.x; t < KN * 64; t += 256) {
    int m = t / 64, c = t % 64;
    sv[m][c] = SIV[m * KC + ci * 64 + c];
  }
  __syncthreads();
  int k = kc * 256 + threadIdx.x;
  if (k >= KHW) return;
  const float* f = feats + ((size_t)n * KC + ci * 64) * KHW + k;
  double acc[KN];
  #pragma unroll
  for (int m = 0; m < KN; m++) acc[m] = 0.0;
  for (int c = 0; c < 64; ++c) {
    double fv = f[(size_t)c * KHW];
    #pragma unroll
    for (int m = 0; m < KN; m++) acc[m] += fv * sv[m][c];
  }
  const size_t str = (size_t)KN * KN * KHW;
  #pragma unroll
  for (int m = 0; m < KN; m++)
    cmp[(size_t)ci * str + ((size_t)n * KN + m) * KHW + k] = acc[m];
}

__global__ void k_cmB(const double* __restrict__ cmp, const double* __restrict__ rnorm,
                      double* __restrict__ cm) {
  size_t t = (size_t)blockIdx.x * 256 + threadIdx.x;
  if (t >= (size_t)KN * KN * KHW) return;
  int k = t % KHW;
  int n = (int)(t / ((size_t)KN * KHW));
  const size_t str = (size_t)KN * KN * KHW;
  double s = 0;
  #pragma unroll
  for (int ci = 0; ci < 8; ci++) s += cmp[ci * str + t];
  cm[t] = s * rnorm[n * KHW + k];
}

__global__ void k_cmnorm(double* __restrict__ cm) {
  double* row = cm + (size_t)blockIdx.x * KHW;
  double s = 0;
  for (int k = threadIdx.x; k < KHW; k += 256) { double v = row[k]; s += v * v; }
  s = blockReduceSumD(s);
  double nn = sqrt(s);
  if (nn < 1e-12) nn = 1e-12;
  double rn = 1.0 / nn;
  for (int k = threadIdx.x; k < KHW; k += 256) row[k] *= rn;
}

__global__ void k_st(const double* __restrict__ cm, double* __restrict__ tbuf) {
  int b = blockIdx.x;
  int n = b / KN, m = b % KN;
  const double* base = cm + (size_t)n * KN * KHW;
  double acc = 0;
  for (int k = threadIdx.x; k < KHW; k += 256) {
    double S = 0;
    #pragma unroll
    for (int mm = 0; mm < KN; mm++) S += base[(size_t)mm * KHW + k];
    acc += base[(size_t)m * KHW + k] * S;
  }
  acc = blockReduceSumD(acc);
  if (threadIdx.x == 0) tbuf[b] = acc;
}

__global__ void k_csa(const double* __restrict__ cm, const double* __restrict__ tbuf,
                      double* __restrict__ CSAd, float* __restrict__ CSAf) {
  __shared__ double w[KN];
  int n = blockIdx.x, tid = threadIdx.x;
  if (tid == 0) {
    double v[KN], mx = -1e300;
    #pragma unroll
    for (int m = 0; m < KN; m++) { v[m] = tbuf[n * KN + m]; mx = fmax(mx, v[m]); }
    double s = 0;
    #pragma unroll
    for (int m = 0; m < KN; m++) { v[m] = exp(v[m] - mx); s += v[m]; }
    #pragma unroll
    for (int m = 0; m < KN; m++) w[m] = v[m] / s;
  }
  __syncthreads();
  double v[7];
  int cnt = 0;
  double lmin = 1e300, lmax = -1e300;
  for (int k = tid; k < KHW; k += 256) {
    double a = 0;
    #pragma unroll
    for (int m = 0; m < KN; m++) a += cm[((size_t)n * KN + m) * KHW + k] * w[m];
    v[cnt++] = a;
    lmin = fmin(lmin, a);
    lmax = fmax(lmax, a);
  }
  double mn = blockReduceMinD(lmin);
  double mx = blockReduceMaxD(lmax);
  double inv = 1.0 / (mx - mn + 1e-12);
  cnt = 0;
  for (int k = tid; k < KHW; k += 256) {
    double nv = (v[cnt++] - mn) * inv;
    CSAd[(size_t)n * KHW + k] = nv;
    CSAf[(size_t)n * KHW + k] = (float)nv;
  }
}

// rank-based stable descending argsort: idx[rank[i]] = i
__global__ void k_rank(const double* __restrict__ CSAd, int* __restrict__ idx) {
  __shared__ double key[KHW];
  int n = blockIdx.y;
  for (int i = threadIdx.x; i < KHW; i += 256) key[i] = CSAd[(size_t)n * KHW + i];
  __syncthreads();
  int i = blockIdx.x * 256 + threadIdx.x;
  if (i >= KHW) return;
  double ki = key[i];
  int r = 0;
  #pragma unroll 4
  for (int j = 0; j < KHW; j++) {
    double kj = key[j];
    r += (kj > ki) || (kj == ki && j < i);
  }
  idx[n * KHW + r] = i;
}

// ---------------- stacked weights (n-independent): w1s[(tau,o)][i] ----------------
__global__ void k_prepw1s(const float* __restrict__ w1, const float* __restrict__ wsc,
                          bf16* __restrict__ w1s) {
  int t = blockIdx.x * 256 + threadIdx.x;   // over KM*KHW
  int m = t / KHW, i = t % KHW;
  int tau = m >> 7, o = m & 127;
  float v = (tau < 9) ? w1[((size_t)o * KHW + i) * 9 + tau]
                      : wsc[(size_t)o * KHW + i];
  w1s[t] = __float2bfloat16(v);
}

__global__ void k_prepw2(const float* __restrict__ w2, bf16* __restrict__ w2p) {
  int t = blockIdx.x * 256 + threadIdx.x;
  if (t >= KOC * 9 * KOC) return;
  int o = t / (9 * KOC), r = t % (9 * KOC);
  int s = r / KOC, i = r % KOC;
  w2p[t] = __float2bfloat16(w2[(size_t)o * 9 * KOC + (size_t)i * 9 + s]);
}

// ---------------- NF column gather: NFcg[n][c][i] = NFT[n][idx[i]][c] ----------------
__global__ void k_gath2(const short* __restrict__ NFT, const int* __restrict__ idx,
                        short* __restrict__ NFcg) {
  __shared__ short T[32][33];
  int i0 = blockIdx.x * 32, c0 = blockIdx.y * 32, n = blockIdx.z;
  int tx = threadIdx.x, ty = threadIdx.y;
  #pragma unroll
  for (int ii = 0; ii < 4; ii++) {
    int row = ty * 4 + ii;
    int id = idx[n * KHW + i0 + row];
    T[row][tx] = NFT[((size_t)n * KHW + id) * KC + c0 + tx];
  }
  __syncthreads();
  #pragma unroll
  for (int ii = 0; ii < 4; ii++) {
    int cl = ty * 4 + ii;
    NFcg[((size_t)n * KC + c0 + cl) * KHW + i0 + tx] = T[tx][cl];
  }
}

// Zpad[n, y+1, x+1, c] = bf16(NFT[n,p,c] * CSA[n,p])
__global__ void k_zprep(const bf16* __restrict__ NFT, const float* __restrict__ CSAf,
                        bf16* __restrict__ Zpad) {
  int t = blockIdx.x * 256 + threadIdx.x;   // over KN*KHW*KC/4
  const int per_n = KHW * (KC / 4);
  int n = t / per_n, r = t % per_n;
  int p = r / (KC / 4), cq = r % (KC / 4);
  float cs = CSAf[n * KHW + p];
  const short* src = (const short*)(NFT + ((size_t)n * KHW + p) * KC) + cq * 4;
  short4v v = *(const short4v*)src;
  short4v o;
  #pragma unroll
  for (int j = 0; j < 4; j++) {
    short s = v[j];
    bf16 hb = *reinterpret_cast<bf16*>(&s);
    bf16 res = __float2bfloat16(__bfloat162float(hb) * cs);
    o[j] = *reinterpret_cast<short*>(&res);
  }
  int y = p / KH, x = p % KH;
  short* dst = (short*)(Zpad + ((size_t)n * KPW * KPW + (size_t)(y + 1) * KPW + (x + 1)) * KC) + cq * 4;
  *(short4v*)dst = o;
}

// ---------------- GEMM1: U = w1s x NFcg, written in conv layout Uc/Usc ----------------
__global__ __launch_bounds__(256) void k_gemmU(const short* __restrict__ w1s,
                                               const short* __restrict__ NFcg,
                                               bf16* __restrict__ Uc,
                                               bf16* __restrict__ Usc) {
  __shared__ short smem[128 * 136];          // aliased As/Bs then Cs
  short* As = smem;                          // [128][40]
  short* Bs = smem + 128 * 40;               // [128][40]
  short* Cs = smem;                          // [128][136]
  int n = blockIdx.z;
  int tau = blockIdx.x;                      // m0 = tau*128
  int m0 = tau * 128, c0 = blockIdx.y * 128;
  int tid = threadIdx.x, lane = tid & 63, wave = tid >> 6;
  int quad = lane >> 4, l15 = lane & 15;
  int wm = (wave & 1) * 64, wn = (wave >> 1) * 64;
  int ar = tid >> 2, ko = (tid & 3) * 8;
  const short* Bb = NFcg + (size_t)n * KC * KHW;
  const short* pa0 = w1s + (size_t)(m0 + ar) * KHW + ko;
  const short* pa1 = w1s + (size_t)(m0 + ar + 64) * KHW + ko;
  const short* pb0 = Bb + (size_t)(c0 + ar) * KHW + ko;
  const short* pb1 = Bb + (size_t)(c0 + ar + 64) * KHW + ko;
  f32x4 acc[4][4] = {};
  for (int k0 = 0; k0 < KHW; k0 += 32) {
    __syncthreads();
    *(float4*)&As[ar * 40 + ko]        = *(const float4*)&pa0[k0];
    *(float4*)&As[(ar + 64) * 40 + ko] = *(const float4*)&pa1[k0];
    *(float4*)&Bs[ar * 40 + ko]        = *(const float4*)&pb0[k0];
    *(float4*)&Bs[(ar + 64) * 40 + ko] = *(const float4*)&pb1[k0];
    __syncthreads();
    short8 a[4], b[4];
    #pragma unroll
    for (int t = 0; t < 4; t++) a[t] = *(const short8*)&As[(wm + t * 16 + l15) * 40 + quad * 8];
    #pragma unroll
    for (int t = 0; t < 4; t++) b[t] = *(const short8*)&Bs[(wn + t * 16 + l15) * 40 + quad * 8];
    #pragma unroll
    for (int ti = 0; ti < 4; ti++)
      #pragma unroll
      for (int tj = 0; tj < 4; tj++)
        acc[ti][tj] = __builtin_amdgcn_mfma_f32_16x16x32_bf16(a[ti], b[tj], acc[ti][tj], 0, 0, 0);
  }
  __syncthreads();   // frag reads done; reuse smem as Cs
  #pragma unroll
  for (int ti = 0; ti < 4; ti++) {
    int lr = wm + ti * 16 + quad * 4;
    #pragma unroll
    for (int tj = 0; tj < 4; tj++) {
      int lc = wn + tj * 16 + l15;
      #pragma unroll
      for (int r = 0; r < 4; r++)
        *(bf16*)&Cs[(lr + r) * 136 + lc] = __float2bfloat16(acc[ti][tj][r]);
    }
  }
  __syncthreads();
  int dyq = tau / 3, dxq = tau % 3;
  #pragma unroll
  for (int pass = 0; pass < 8; pass++) {
    int row = pass * 16 + (tid >> 4);
    int col = (tid & 15) * 8;
    if (tau < 9) {
      *(float4*)&Uc[((size_t)((n * 3 + dyq) * 128 + row)) * 1536 + dxq * 512 + c0 + col] =
          *(const float4*)&Cs[row * 136 + col];
    } else {
      *(float4*)&Usc[((size_t)(n * 128 + row)) * 512 + c0 + col] =
          *(const float4*)&Cs[row * 136 + col];
    }
  }
}

// ---------------- convh: h partials via 3x3 conv over Z (512ch -> 128) ----------------
// dy<3: Hpart[dy][n][o][p] = sum_dx sum_c Uc[n,dy][o][dx*512+c] * Zpad[y0+dy][x0+dx][c]
// dy==3: shortcut Hpart[3][n][o][p] = sum_c Usc[n][o][c] * Zpad[y0+1][x0+1][c]
__global__ __launch_bounds__(256) void k_convh(const short* __restrict__ Uc,
                                               const short* __restrict__ Usc,
                                               const short* __restrict__ Zpad,
                                               float* __restrict__ Hpart) {
  __shared__ short As[128][40];
  __shared__ short Bs[64][40];
  int p0 = blockIdx.x * 64, dy = blockIdx.y, n = blockIdx.z;
  int tid = threadIdx.x, lane = tid & 63, wave = tid >> 6;
  int quad = lane >> 4, l15 = lane & 15;
  int wm = (wave & 1) * 64, wn = (wave >> 1) * 32;
  int ar = tid >> 2, ko = (tid & 3) * 8;
  const short* Zb = Zpad + (size_t)n * KPW * KPW * KC;
  int p = p0 + ar;
  int y0 = p / KH, x0 = p % KH;
  bool isconv = (dy < 3);
  const short* Abase = isconv ? Uc + ((size_t)(n * 3 + dy) * 128) * 1536
                              : Usc + (size_t)n * 128 * 512;
  int astr = isconv ? 1536 : 512;
  int ndx = isconv ? 3 : 1;
  f32x4 acc[4][2] = {};
  for (int dx = 0; dx < ndx; ++dx) {
    int yy = isconv ? (y0 + dy) : (y0 + 1);
    int xx = isconv ? (x0 + dx) : (x0 + 1);
    const short* a0 = Abase + (size_t)ar * astr + dx * 512 + ko;
    const short* a1 = Abase + (size_t)(ar + 64) * astr + dx * 512 + ko;
    const short* b0 = Zb + ((size_t)yy * KPW + xx) * KC + ko;
    for (int k0 = 0; k0 < KC; k0 += 32) {
      __syncthreads();
      *(float4*)&As[ar][ko]      = *(const float4*)&a0[k0];
      *(float4*)&As[ar + 64][ko] = *(const float4*)&a1[k0];
      *(float4*)&Bs[ar][ko]      = *(const float4*)&b0[k0];
      __syncthreads();
      short8 a[4], b[2];
      #pragma unroll
      for (int t = 0; t < 4; t++) a[t] = *(const short8*)&As[wm + t * 16 + l15][quad * 8];
      #pragma unroll
      for (int t = 0; t < 2; t++) b[t] = *(const short8*)&Bs[wn + t * 16 + l15][quad * 8];
      #pragma unroll
      for (int ti = 0; ti < 4; ti++)
        #pragma unroll
        for (int tj = 0; tj < 2; tj++)
          acc[ti][tj] = __builtin_amdgcn_mfma_f32_16x16x32_bf16(a[ti], b[tj], acc[ti][tj], 0, 0, 0);
    }
  }
  float* cb = Hpart + ((size_t)(dy * KN + n)) * KOC * KHW;
  for (int ti = 0; ti < 4; ti++) {
    int o = wm + ti * 16 + quad * 4;
    for (int tj = 0; tj < 2; tj++) {
      int q = p0 + wn + tj * 16 + l15;
      #pragma unroll
      for (int r = 0; r < 4; r++)
        cb[(size_t)(o + r) * KHW + q] = acc[ti][tj][r];
    }
  }
}

// hpadT[n, y+1, x+1, o] = bf16(relu(b1[o] + Hpart[0]+Hpart[1]+Hpart[2]))
__global__ void k_hprep3(const float* __restrict__ Hpart, const float* __restrict__ b1,
                         bf16* __restrict__ hpadT) {
  __shared__ float T[32][132];
  int n = blockIdx.y, p0 = blockIdx.x * 32;
  int tx = threadIdx.x, ty = threadIdx.y;
  const size_t str = (size_t)KN * KOC * KHW;
  const float* hb = Hpart + (size_t)n * KOC * KHW;
  #pragma unroll
  for (int oc = 0; oc < 16; oc++) {
    int o = oc * 8 + ty;
    size_t off = (size_t)o * KHW + p0 + tx;
    T[tx][o] = fmaxf(hb[off] + hb[str + off] + hb[2 * str + off] + b1[o], 0.0f);
  }
  __syncthreads();
  bf16* hp = hpadT + (size_t)n * KPW * KPW * KOC;
  #pragma unroll
  for (int pc = 0; pc < 4; pc++) {
    int pl = ty * 4 + pc;
    int pp = p0 + pl;
    int yy = pp / KH, xx = pp % KH;
    bf16* row = hp + ((size_t)(yy + 1) * KPW + (xx + 1)) * KOC;
    #pragma unroll
    for (int u = 0; u < 4; u++) row[tx * 4 + u] = __float2bfloat16(T[pl][tx * 4 + u]);
  }
}

// ---------------- conv2 (3x3, 128->128): 128x64 tile, dy-split to dense partials ----------------
__global__ __launch_bounds__(256) void k_conv2(const short* __restrict__ w2p,
                                               const short* __restrict__ hpadT,
                                               float* __restrict__ Cpart) {
  __shared__ short As[128][40];
  __shared__ short Bs[64][40];
  int p0 = blockIdx.x * 64, dy = blockIdx.y, n = blockIdx.z;
  int tid = threadIdx.x, lane = tid & 63, wave = tid >> 6;
  int quad = lane >> 4, l15 = lane & 15;
  int wm = (wave & 1) * 64, wn = (wave >> 1) * 32;
  int ar = tid >> 2, ko = (tid & 3) * 8;
  const short* hb = hpadT + (size_t)n * KPW * KPW * KOC;
  int p = p0 + ar;
  int y0 = p / KH, x0 = p % KH;
  f32x4 acc[4][2] = {};
  for (int dx = 0; dx < 3; ++dx) {
    const short* a0 = w2p + (size_t)ar * 9 * KOC + (dy * 3 + dx) * KOC + ko;
    const short* a1 = w2p + (size_t)(ar + 64) * 9 * KOC + (dy * 3 + dx) * KOC + ko;
    const short* b0 = hb + ((size_t)(y0 + dy) * KPW + (x0 + dx)) * KOC + ko;
    for (int k0 = 0; k0 < KOC; k0 += 32) {
      __syncthreads();
      *(float4*)&As[ar][ko]      = *(const float4*)&a0[k0];
      *(float4*)&As[ar + 64][ko] = *(const float4*)&a1[k0];
      *(float4*)&Bs[ar][ko]      = *(const float4*)&b0[k0];
      __syncthreads();
      short8 a[4], b[2];
      #pragma unroll
      for (int t = 0; t < 4; t++) a[t] = *(const short8*)&As[wm + t * 16 + l15][quad * 8];
      #pragma unroll
      for (int t = 0; t < 2; t++) b[t] = *(const short8*)&Bs[wn + t * 16 + l15][quad * 8];
      #pragma unroll
      for (int ti = 0; ti < 4; ti++)
        #pragma unroll
        for (int tj = 0; tj < 2; tj++)
          acc[ti][tj] = __builtin_amdgcn_mfma_f32_16x16x32_bf16(a[ti], b[tj], acc[ti][tj], 0, 0, 0);
    }
  }
  float* cb = Cpart + ((size_t)(dy * KN + n)) * KOC * KHW;
  for (int ti = 0; ti < 4; ti++) {
    int o = wm + ti * 16 + quad * 4;
    for (int tj = 0; tj < 2; tj++) {
      int q = p0 + wn + tj * 16 + l15;
      #pragma unroll
      for (int r = 0; r < 4; r++)
        cb[(size_t)(o + r) * KHW + q] = acc[ti][tj][r];
    }
  }
}

// out = relu(sum_dy Cpart + b2 + shortcut(Hpart[3]) + bs)
__global__ void k_final2(const float* __restrict__ Cpart, const float* __restrict__ Hpart,
                         const float* __restrict__ b2, const float* __restrict__ bs,
                         float* __restrict__ out) {
  int t = blockIdx.x * 256 + threadIdx.x;
  if (t >= KN * KOC * KHW) return;
  int o = (t / KHW) % KOC;
  const size_t stride = (size_t)KN * KOC * KHW;
  float v = Cpart[t] + Cpart[stride + t] + Cpart[2 * stride + t] +
            Hpart[3 * stride + t] + b2[o] + bs[o];
  out[t] = fmaxf(v, 0.0f);
}

// ---------------- launch ----------------
extern "C" void kernel_launch(void* const* d_in, const int* in_sizes, int n_in,
                              void* d_out, int out_size, void* d_ws, size_t ws_size,
                              hipStream_t stream) {
  const float* feats = (const float*)d_in[0];
  const float* sisms = (const float*)d_in[1];
  const float* w1 = (const float*)d_in[2];
  const float* b1 = (const float*)d_in[3];
  const float* w2 = (const float*)d_in[4];
  const float* b2 = (const float*)d_in[5];
  const float* wsc = (const float*)d_in[6];
  const float* bsc = (const float*)d_in[7];
  float* out = (float*)d_out;

  char* w = (char*)d_ws;
  auto carve = [&](size_t bytes) -> void* {
    void* p = (void*)w;
    w += (bytes + 255) & ~(size_t)255;
    return p;
  };
  bf16* NFT   = (bf16*)carve((size_t)KN * KHW * KC * 2);          // 16.4 MB
  bf16* NFcg  = (bf16*)carve((size_t)KN * KC * KHW * 2);          // 16.4 MB
  bf16* Uc    = (bf16*)carve((size_t)KN * 3 * 128 * 1536 * 2);    // 11.8 MB
  bf16* Usc   = (bf16*)carve((size_t)KN * 128 * 512 * 2);         // 1.3 MB
  bf16* w1s   = (bf16*)carve((size_t)KM * KHW * 2);               // 4.1 MB
  bf16* Zpad  = (bf16*)carve((size_t)KN * KPW * KPW * KC * 2);    // 18.1 MB
  bf16* hpadT = (bf16*)carve((size_t)KN * KPW * KPW * KOC * 2);   // 4.5 MB
  float* Hpart = (float*)carve((size_t)4 * KN * KOC * KHW * 4);   // 32.8 MB
  float* Cpart = (float*)carve((size_t)3 * KN * KOC * KHW * 4);   // 24.6 MB
  bf16* w2p   = (bf16*)carve((size_t)KOC * 9 * KOC * 2);
  double* psbuf = (double*)carve((size_t)4 * KN * KHW * 8);
  double* rnorm = (double*)carve((size_t)KN * KHW * 8);
  double* vpp   = (double*)carve((size_t)KN * KC * 50 * 8);       // 2.05 MB
  double* SIV   = (double*)carve((size_t)KN * KC * 8);
  double* cmp   = (double*)carve((size_t)8 * KN * KN * KHW * 8);  // 10.2 MB
  double* cm    = (double*)carve((size_t)KN * KN * KHW * 8);
  double* tbuf  = (double*)carve((size_t)KN * KN * 8);
  double* CSAd  = (double*)carve((size_t)KN * KHW * 8);
  float* CSAf   = (float*)carve((size_t)KN * KHW * 4);
  int* idxb     = (int*)carve((size_t)KN * KHW * 4);

  hipMemsetAsync(hpadT, 0, (size_t)KN * KPW * KPW * KOC * 2, stream);
  hipMemsetAsync(Zpad, 0, (size_t)KN * KPW * KPW * KC * 2, stream);

  k_rnormp<<<dim3(63, 4), 256, 0, stream>>>(feats, psbuf);
  k_rnormc<<<63, 256, 0, stream>>>(psbuf, rnorm);
  k_nft<<<dim3(50, 16, KN), dim3(32, 8), 0, stream>>>(feats, rnorm, sisms, NFT, vpp);
  k_sivnorm2<<<KN, 512, 0, stream>>>(vpp, SIV);
  k_cmP<<<dim3(7, 8, KN), 256, 0, stream>>>(feats, SIV, cmp);
  k_cmB<<<625, 256, 0, stream>>>(cmp, rnorm, cm);
  k_cmnorm<<<KN * KN, 256, 0, stream>>>(cm);
  k_st<<<KN * KN, 256, 0, stream>>>(cm, tbuf);
  k_csa<<<KN, 256, 0, stream>>>(cm, tbuf, CSAd, CSAf);
  k_rank<<<dim3(7, KN), 256, 0, stream>>>(CSAd, idxb);

  k_prepw1s<<<KM * KHW / 256, 256, 0, stream>>>(w1, wsc, w1s);
  k_prepw2<<<576, 256, 0, stream>>>(w2, w2p);
  k_gath2<<<dim3(50, 16, KN), dim3(32, 8), 0, stream>>>((const short*)NFT, idxb, (short*)NFcg);
  k_zprep<<<KN * KHW * (KC / 4) / 256, 256, 0, stream>>>(NFT, CSAf, Zpad);

  k_gemmU<<<dim3(10, 4, KN), 256, 0, stream>>>((const short*)w1s, (const short*)NFcg, Uc, Usc);
  k_convh<<<dim3(25, 4, KN), 256, 0, stream>>>((const short*)Uc, (const short*)Usc,
                                               (const short*)Zpad, Hpart);
  k_hprep3<<<dim3(50, KN), dim3(32, 8), 0, stream>>>(Hpart, b1, hpadT);
  k_conv2<<<dim3(25, 3, KN), 256, 0, stream>>>((const short*)w2p, (const short*)hpadT, Cpart);
  k_final2<<<8000, 256, 0, stream>>>(Cpart, Hpart, b2, bsc, out);
}

// Round 10
// 362.194 us; speedup vs baseline: 1.2345x; 1.0217x over previous
//
#include <hip/hip_runtime.h>
#include <hip/hip_bf16.h>
#include <math.h>

typedef short short8 __attribute__((ext_vector_type(8)));
typedef short short4v __attribute__((ext_vector_type(4)));
typedef float f32x4 __attribute__((ext_vector_type(4)));
typedef __hip_bfloat16 bf16;

// problem constants
#define KN 10
#define KC 512
#define KHW 1600
#define KH 40
#define KOC 128
#define KPW 42   // padded spatial (40+2)
#define KM 1280  // stacked M: 9 conv taps * 128 + 128 shortcut

// ---------------- block reduction helpers (fp64) ----------------
__device__ __forceinline__ double blockReduceSumD(double v) {
  __shared__ double tmpS[8];
  int lane = threadIdx.x & 63, wv = threadIdx.x >> 6;
  #pragma unroll
  for (int o = 32; o > 0; o >>= 1) v += __shfl_down(v, o);
  if (lane == 0) tmpS[wv] = v;
  __syncthreads();
  if (threadIdx.x == 0) {
    int nw = (blockDim.x + 63) >> 6;
    double s = 0;
    for (int i = 0; i < nw; i++) s += tmpS[i];
    tmpS[0] = s;
  }
  __syncthreads();
  double r = tmpS[0];
  __syncthreads();
  return r;
}

__device__ __forceinline__ double blockReduceMinD(double v) {
  __shared__ double tmpMn[8];
  int lane = threadIdx.x & 63, wv = threadIdx.x >> 6;
  #pragma unroll
  for (int o = 32; o > 0; o >>= 1) v = fmin(v, __shfl_down(v, o));
  if (lane == 0) tmpMn[wv] = v;
  __syncthreads();
  if (threadIdx.x == 0) {
    int nw = (blockDim.x + 63) >> 6;
    double s = tmpMn[0];
    for (int i = 1; i < nw; i++) s = fmin(s, tmpMn[i]);
    tmpMn[0] = s;
  }
  __syncthreads();
  double r = tmpMn[0];
  __syncthreads();
  return r;
}

__device__ __forceinline__ double blockReduceMaxD(double v) {
  __shared__ double tmpMx[8];
  int lane = threadIdx.x & 63, wv = threadIdx.x >> 6;
  #pragma unroll
  for (int o = 32; o > 0; o >>= 1) v = fmax(v, __shfl_down(v, o));
  if (lane == 0) tmpMx[wv] = v;
  __syncthreads();
  if (threadIdx.x == 0) {
    int nw = (blockDim.x + 63) >> 6;
    double s = tmpMx[0];
    for (int i = 1; i < nw; i++) s = fmax(s, tmpMx[i]);
    tmpMx[0] = s;
  }
  __syncthreads();
  double r = tmpMx[0];
  __syncthreads();
  return r;
}

// ---------------- small chain (fp64 for argsort stability) ----------------

__global__ void k_rnormp(const float* __restrict__ feats, double* __restrict__ ps) {
  int t = blockIdx.x * 256 + threadIdx.x;
  if (t >= KN * KHW) return;
  int ci = blockIdx.y;
  int n = t / KHW, k = t % KHW;
  const float* p = feats + (size_t)n * KC * KHW + (size_t)ci * 128 * KHW + k;
  double s = 0.0;
  for (int c = 0; c < 128; ++c) { double v = p[(size_t)c * KHW]; s += v * v; }
  ps[(size_t)ci * KN * KHW + t] = s;
}

__global__ void k_rnormc(const double* __restrict__ ps, double* __restrict__ rnorm) {
  int t = blockIdx.x * 256 + threadIdx.x;
  if (t >= KN * KHW) return;
  double s = ps[t] + ps[KN * KHW + t] + ps[2 * KN * KHW + t] + ps[3 * KN * KHW + t];
  double nn = sqrt(s);
  if (nn < 1e-12) nn = 1e-12;
  rnorm[t] = 1.0 / nn;
}

// NFT[n,k,c] = bf16(feats[n,c,k] * rnorm[n,k]); also emits SIV pre-partials
__global__ void k_nft(const float* __restrict__ feats, const double* __restrict__ rnorm,
                      const float* __restrict__ sism, bf16* __restrict__ NFT,
                      double* __restrict__ vpp) {
  __shared__ float T[32][33];
  int n = blockIdx.z, k0 = blockIdx.x * 32, c0 = blockIdx.y * 32;
  int tx = threadIdx.x, ty = threadIdx.y;
  const float* fb = feats + ((size_t)n * KC + c0) * KHW + k0;
  #pragma unroll
  for (int ii = 0; ii < 4; ii++) {
    int cl = ty * 4 + ii;
    T[cl][tx] = fb[(size_t)cl * KHW + tx];
  }
  __syncthreads();
  bf16* ob = NFT + ((size_t)n * KHW + k0) * KC + c0;
  #pragma unroll
  for (int ii = 0; ii < 4; ii++) {
    int kl = ty * 4 + ii;
    float r = (float)rnorm[n * KHW + k0 + kl];
    ob[(size_t)kl * KC + tx] = __float2bfloat16(T[tx][kl] * r);
  }
  double rs = rnorm[n * KHW + k0 + tx] * (double)sism[n * KHW + k0 + tx];
  #pragma unroll
  for (int ii = 0; ii < 4; ii++) {
    int cl = ty * 4 + ii;
    double v = (double)T[cl][tx] * rs;
    #pragma unroll
    for (int o = 16; o > 0; o >>= 1) v += __shfl_down(v, o, 32);
    if (tx == 0) vpp[((size_t)n * KC + c0 + cl) * 50 + k0 / 32] = v;
  }
}

__global__ void k_sivnorm2(const double* __restrict__ vpp, double* __restrict__ SIV) {
  int n = blockIdx.x, c = threadIdx.x;   // 512 threads
  const double* p = vpp + ((size_t)n * KC + c) * 50;
  double acc = 0;
  #pragma unroll 5
  for (int j = 0; j < 50; j++) acc += p[j];
  acc /= (double)KHW;
  double s2 = blockReduceSumD(acc * acc);
  double nn = sqrt(s2);
  if (nn < 1e-12) nn = 1e-12;
  SIV[n * KC + c] = acc / nn;
}

__global__ void k_cmP(const float* __restrict__ feats, const double* __restrict__ SIV,
                      double* __restrict__ cmp) {
  __shared__ double sv[KN][64];
  int kc = blockIdx.x, ci = blockIdx.y, n = blockIdx.z;
  for (int t = threadIdx.x; t < KN * 64; t += 256) {
    int m = t / 64, c = t % 64;
    sv[m][c] = SIV[m * KC + ci * 64 + c];
  }
  __syncthreads();
  int k = kc * 256 + threadIdx.x;
  if (k >= KHW) return;
  const float* f = feats + ((size_t)n * KC + ci * 64) * KHW + k;
  double acc[KN];
  #pragma unroll
  for (int m = 0; m < KN; m++) acc[m] = 0.0;
  for (int c = 0; c < 64; ++c) {
    double fv = f[(size_t)c * KHW];
    #pragma unroll
    for (int m = 0; m < KN; m++) acc[m] += fv * sv[m][c];
  }
  const size_t str = (size_t)KN * KN * KHW;
  #pragma unroll
  for (int m = 0; m < KN; m++)
    cmp[(size_t)ci * str + ((size_t)n * KN + m) * KHW + k] = acc[m];
}

__global__ void k_cmB(const double* __restrict__ cmp, const double* __restrict__ rnorm,
                      double* __restrict__ cm) {
  size_t t = (size_t)blockIdx.x * 256 + threadIdx.x;
  if (t >= (size_t)KN * KN * KHW) return;
  int k = t % KHW;
  int n = (int)(t / ((size_t)KN * KHW));
  const size_t str = (size_t)KN * KN * KHW;
  double s = 0;
  #pragma unroll
  for (int ci = 0; ci < 8; ci++) s += cmp[ci * str + t];
  cm[t] = s * rnorm[n * KHW + k];
}

__global__ void k_cmnorm(double* __restrict__ cm) {
  double* row = cm + (size_t)blockIdx.x * KHW;
  double s = 0;
  for (int k = threadIdx.x; k < KHW; k += 256) { double v = row[k]; s += v * v; }
  s = blockReduceSumD(s);
  double nn = sqrt(s);
  if (nn < 1e-12) nn = 1e-12;
  double rn = 1.0 / nn;
  for (int k = threadIdx.x; k < KHW; k += 256) row[k] *= rn;
}

__global__ void k_st(const double* __restrict__ cm, double* __restrict__ tbuf) {
  int b = blockIdx.x;
  int n = b / KN, m = b % KN;
  const double* base = cm + (size_t)n * KN * KHW;
  double acc = 0;
  for (int k = threadIdx.x; k < KHW; k += 256) {
    double S = 0;
    #pragma unroll
    for (int mm = 0; mm < KN; mm++) S += base[(size_t)mm * KHW + k];
    acc += base[(size_t)m * KHW + k] * S;
  }
  acc = blockReduceSumD(acc);
  if (threadIdx.x == 0) tbuf[b] = acc;
}

__global__ void k_csa(const double* __restrict__ cm, const double* __restrict__ tbuf,
                      double* __restrict__ CSAd, float* __restrict__ CSAf) {
  __shared__ double w[KN];
  int n = blockIdx.x, tid = threadIdx.x;
  if (tid == 0) {
    double v[KN], mx = -1e300;
    #pragma unroll
    for (int m = 0; m < KN; m++) { v[m] = tbuf[n * KN + m]; mx = fmax(mx, v[m]); }
    double s = 0;
    #pragma unroll
    for (int m = 0; m < KN; m++) { v[m] = exp(v[m] - mx); s += v[m]; }
    #pragma unroll
    for (int m = 0; m < KN; m++) w[m] = v[m] / s;
  }
  __syncthreads();
  double v[7];
  int cnt = 0;
  double lmin = 1e300, lmax = -1e300;
  for (int k = tid; k < KHW; k += 256) {
    double a = 0;
    #pragma unroll
    for (int m = 0; m < KN; m++) a += cm[((size_t)n * KN + m) * KHW + k] * w[m];
    v[cnt++] = a;
    lmin = fmin(lmin, a);
    lmax = fmax(lmax, a);
  }
  double mn = blockReduceMinD(lmin);
  double mx = blockReduceMaxD(lmax);
  double inv = 1.0 / (mx - mn + 1e-12);
  cnt = 0;
  for (int k = tid; k < KHW; k += 256) {
    double nv = (v[cnt++] - mn) * inv;
    CSAd[(size_t)n * KHW + k] = nv;
    CSAf[(size_t)n * KHW + k] = (float)nv;
  }
}

// rank-based stable descending argsort: idx[rank[i]] = i
__global__ void k_rank(const double* __restrict__ CSAd, int* __restrict__ idx) {
  __shared__ double key[KHW];
  int n = blockIdx.y;
  for (int i = threadIdx.x; i < KHW; i += 256) key[i] = CSAd[(size_t)n * KHW + i];
  __syncthreads();
  int i = blockIdx.x * 256 + threadIdx.x;
  if (i >= KHW) return;
  double ki = key[i];
  int r = 0;
  #pragma unroll 4
  for (int j = 0; j < KHW; j++) {
    double kj = key[j];
    r += (kj > ki) || (kj == ki && j < i);
  }
  idx[n * KHW + r] = i;
}

// ---------------- stacked weights (n-independent): w1s[(tau,o)][i] ----------------
__global__ void k_prepw1s(const float* __restrict__ w1, const float* __restrict__ wsc,
                          bf16* __restrict__ w1s) {
  int t = blockIdx.x * 256 + threadIdx.x;   // over KM*KHW
  int m = t / KHW, i = t % KHW;
  int tau = m >> 7, o = m & 127;
  float v = (tau < 9) ? w1[((size_t)o * KHW + i) * 9 + tau]
                      : wsc[(size_t)o * KHW + i];
  w1s[t] = __float2bfloat16(v);
}

__global__ void k_prepw2(const float* __restrict__ w2, bf16* __restrict__ w2p) {
  int t = blockIdx.x * 256 + threadIdx.x;
  if (t >= KOC * 9 * KOC) return;
  int o = t / (9 * KOC), r = t % (9 * KOC);
  int s = r / KOC, i = r % KOC;
  w2p[t] = __float2bfloat16(w2[(size_t)o * 9 * KOC + (size_t)i * 9 + s]);
}

// ---------------- NF column gather: NFcg[n][c][i] = NFT[n][idx[i]][c] ----------------
__global__ void k_gath2(const short* __restrict__ NFT, const int* __restrict__ idx,
                        short* __restrict__ NFcg) {
  __shared__ short T[32][33];
  int i0 = blockIdx.x * 32, c0 = blockIdx.y * 32, n = blockIdx.z;
  int tx = threadIdx.x, ty = threadIdx.y;
  #pragma unroll
  for (int ii = 0; ii < 4; ii++) {
    int row = ty * 4 + ii;
    int id = idx[n * KHW + i0 + row];
    T[row][tx] = NFT[((size_t)n * KHW + id) * KC + c0 + tx];
  }
  __syncthreads();
  #pragma unroll
  for (int ii = 0; ii < 4; ii++) {
    int cl = ty * 4 + ii;
    NFcg[((size_t)n * KC + c0 + cl) * KHW + i0 + tx] = T[tx][cl];
  }
}

// Zpad[n, y+1, x+1, c] = bf16(NFT[n,p,c] * CSA[n,p])
__global__ void k_zprep(const bf16* __restrict__ NFT, const float* __restrict__ CSAf,
                        bf16* __restrict__ Zpad) {
  int t = blockIdx.x * 256 + threadIdx.x;   // over KN*KHW*KC/4
  const int per_n = KHW * (KC / 4);
  int n = t / per_n, r = t % per_n;
  int p = r / (KC / 4), cq = r % (KC / 4);
  float cs = CSAf[n * KHW + p];
  const short* src = (const short*)(NFT + ((size_t)n * KHW + p) * KC) + cq * 4;
  short4v v = *(const short4v*)src;
  short4v o;
  #pragma unroll
  for (int j = 0; j < 4; j++) {
    short s = v[j];
    bf16 hb = *reinterpret_cast<bf16*>(&s);
    bf16 res = __float2bfloat16(__bfloat162float(hb) * cs);
    o[j] = *reinterpret_cast<short*>(&res);
  }
  int y = p / KH, x = p % KH;
  short* dst = (short*)(Zpad + ((size_t)n * KPW * KPW + (size_t)(y + 1) * KPW + (x + 1)) * KC) + cq * 4;
  *(short4v*)dst = o;
}

// ---------------- GEMM1: U = w1s x NFcg, conv layout; XCD-swizzled 1D grid ----------------
// 400 blocks = 8 xcd * (5 (n,c0) pairs * 10 tau)
__global__ __launch_bounds__(256) void k_gemmU(const short* __restrict__ w1s,
                                               const short* __restrict__ NFcg,
                                               bf16* __restrict__ Uc,
                                               bf16* __restrict__ Usc) {
  __shared__ short smem[128 * 136];          // aliased As/Bs then Cs
  short* As = smem;                          // [128][40]
  short* Bs = smem + 128 * 40;               // [128][40]
  short* Cs = smem;                          // [128][136]
  int b = blockIdx.x;
  int xcd = b & 7, slot = b >> 3;            // slot 0..49
  int pair = xcd * 5 + slot / 10;            // 0..39 : (n, c0-tile)
  int tau = slot % 10;
  int n = pair >> 2, c0 = (pair & 3) * 128;
  int m0 = tau * 128;
  int tid = threadIdx.x, lane = tid & 63, wave = tid >> 6;
  int quad = lane >> 4, l15 = lane & 15;
  int wm = (wave & 1) * 64, wn = (wave >> 1) * 64;
  int ar = tid >> 2, ko = (tid & 3) * 8;
  const short* Bb = NFcg + (size_t)n * KC * KHW;
  const short* pa0 = w1s + (size_t)(m0 + ar) * KHW + ko;
  const short* pa1 = w1s + (size_t)(m0 + ar + 64) * KHW + ko;
  const short* pb0 = Bb + (size_t)(c0 + ar) * KHW + ko;
  const short* pb1 = Bb + (size_t)(c0 + ar + 64) * KHW + ko;
  f32x4 acc[4][4] = {};
  for (int k0 = 0; k0 < KHW; k0 += 32) {
    __syncthreads();
    *(float4*)&As[ar * 40 + ko]        = *(const float4*)&pa0[k0];
    *(float4*)&As[(ar + 64) * 40 + ko] = *(const float4*)&pa1[k0];
    *(float4*)&Bs[ar * 40 + ko]        = *(const float4*)&pb0[k0];
    *(float4*)&Bs[(ar + 64) * 40 + ko] = *(const float4*)&pb1[k0];
    __syncthreads();
    short8 a[4], bb[4];
    #pragma unroll
    for (int t = 0; t < 4; t++) a[t] = *(const short8*)&As[(wm + t * 16 + l15) * 40 + quad * 8];
    #pragma unroll
    for (int t = 0; t < 4; t++) bb[t] = *(const short8*)&Bs[(wn + t * 16 + l15) * 40 + quad * 8];
    #pragma unroll
    for (int ti = 0; ti < 4; ti++)
      #pragma unroll
      for (int tj = 0; tj < 4; tj++)
        acc[ti][tj] = __builtin_amdgcn_mfma_f32_16x16x32_bf16(a[ti], bb[tj], acc[ti][tj], 0, 0, 0);
  }
  __syncthreads();   // frag reads done; reuse smem as Cs
  #pragma unroll
  for (int ti = 0; ti < 4; ti++) {
    int lr = wm + ti * 16 + quad * 4;
    #pragma unroll
    for (int tj = 0; tj < 4; tj++) {
      int lc = wn + tj * 16 + l15;
      #pragma unroll
      for (int r = 0; r < 4; r++)
        *(bf16*)&Cs[(lr + r) * 136 + lc] = __float2bfloat16(acc[ti][tj][r]);
    }
  }
  __syncthreads();
  int dyq = tau / 3, dxq = tau % 3;
  #pragma unroll
  for (int pass = 0; pass < 8; pass++) {
    int row = pass * 16 + (tid >> 4);
    int col = (tid & 15) * 8;
    if (tau < 9) {
      *(float4*)&Uc[((size_t)((n * 3 + dyq) * 128 + row)) * 1536 + dxq * 512 + c0 + col] =
          *(const float4*)&Cs[row * 136 + col];
    } else {
      *(float4*)&Usc[((size_t)(n * 128 + row)) * 512 + c0 + col] =
          *(const float4*)&Cs[row * 136 + col];
    }
  }
}

// ---------------- convh: 128-wide tiles, XCD-swizzled 1D grid ----------------
// 520 blocks = 8 xcd * (5 (n,dy) pairs * 13 p-tiles)
// dy<3: Hpart[dy][n][o][p] = sum_dx sum_c Uc[n,dy][o][dx*512+c] * Zpad[y0+dy][x0+dx][c]
// dy==3: shortcut via Usc, K=512
__global__ __launch_bounds__(256) void k_convh(const short* __restrict__ Uc,
                                               const short* __restrict__ Usc,
                                               const short* __restrict__ Zpad,
                                               float* __restrict__ Hpart) {
  __shared__ short As[128][40];
  __shared__ short Bs[128][40];
  int b = blockIdx.x;
  int xcd = b & 7, slot = b >> 3;            // slot 0..64
  int pair = xcd * 5 + slot / 13;            // 0..39 : (n, dy)
  int pt = slot % 13;
  int n = pair >> 2, dy = pair & 3;
  int p0 = pt * 128;
  int tid = threadIdx.x, lane = tid & 63, wave = tid >> 6;
  int quad = lane >> 4, l15 = lane & 15;
  int wm = (wave & 1) * 64, wn = (wave >> 1) * 64;
  int ar = tid >> 2, ko = (tid & 3) * 8;
  const short* Zb = Zpad + (size_t)n * KPW * KPW * KC;
  int pr0 = min(p0 + ar, KHW - 1), pr1 = min(p0 + ar + 64, KHW - 1);
  int y0 = pr0 / KH, x0 = pr0 % KH;
  int y1 = pr1 / KH, x1 = pr1 % KH;
  bool isconv = (dy < 3);
  const short* Abase = isconv ? Uc + ((size_t)(n * 3 + dy) * 128) * 1536
                              : Usc + (size_t)n * 128 * 512;
  int astr = isconv ? 1536 : 512;
  int ndx = isconv ? 3 : 1;
  f32x4 acc[4][4] = {};
  for (int dx = 0; dx < ndx; ++dx) {
    int yy0 = isconv ? (y0 + dy) : (y0 + 1);
    int xx0 = isconv ? (x0 + dx) : (x0 + 1);
    int yy1 = isconv ? (y1 + dy) : (y1 + 1);
    int xx1 = isconv ? (x1 + dx) : (x1 + 1);
    const short* a0 = Abase + (size_t)ar * astr + dx * 512 + ko;
    const short* a1 = Abase + (size_t)(ar + 64) * astr + dx * 512 + ko;
    const short* b0 = Zb + ((size_t)yy0 * KPW + xx0) * KC + ko;
    const short* b1 = Zb + ((size_t)yy1 * KPW + xx1) * KC + ko;
    for (int k0 = 0; k0 < KC; k0 += 32) {
      __syncthreads();
      *(float4*)&As[ar][ko]      = *(const float4*)&a0[k0];
      *(float4*)&As[ar + 64][ko] = *(const float4*)&a1[k0];
      *(float4*)&Bs[ar][ko]      = *(const float4*)&b0[k0];
      *(float4*)&Bs[ar + 64][ko] = *(const float4*)&b1[k0];
      __syncthreads();
      short8 a[4], bb[4];
      #pragma unroll
      for (int t = 0; t < 4; t++) a[t] = *(const short8*)&As[wm + t * 16 + l15][quad * 8];
      #pragma unroll
      for (int t = 0; t < 4; t++) bb[t] = *(const short8*)&Bs[wn + t * 16 + l15][quad * 8];
      #pragma unroll
      for (int ti = 0; ti < 4; ti++)
        #pragma unroll
        for (int tj = 0; tj < 4; tj++)
          acc[ti][tj] = __builtin_amdgcn_mfma_f32_16x16x32_bf16(a[ti], bb[tj], acc[ti][tj], 0, 0, 0);
    }
  }
  float* cb = Hpart + ((size_t)(dy * KN + n)) * KOC * KHW;
  for (int ti = 0; ti < 4; ti++) {
    int o = wm + ti * 16 + quad * 4;
    for (int tj = 0; tj < 4; tj++) {
      int q = p0 + wn + tj * 16 + l15;
      if (q < KHW) {
        #pragma unroll
        for (int r = 0; r < 4; r++)
          cb[(size_t)(o + r) * KHW + q] = acc[ti][tj][r];
      }
    }
  }
}

// hpadT[n, y+1, x+1, o] = bf16(relu(b1[o] + Hpart[0]+Hpart[1]+Hpart[2]))
__global__ void k_hprep3(const float* __restrict__ Hpart, const float* __restrict__ b1,
                         bf16* __restrict__ hpadT) {
  __shared__ float T[32][132];
  int n = blockIdx.y, p0 = blockIdx.x * 32;
  int tx = threadIdx.x, ty = threadIdx.y;
  const size_t str = (size_t)KN * KOC * KHW;
  const float* hb = Hpart + (size_t)n * KOC * KHW;
  #pragma unroll
  for (int oc = 0; oc < 16; oc++) {
    int o = oc * 8 + ty;
    size_t off = (size_t)o * KHW + p0 + tx;
    T[tx][o] = fmaxf(hb[off] + hb[str + off] + hb[2 * str + off] + b1[o], 0.0f);
  }
  __syncthreads();
  bf16* hp = hpadT + (size_t)n * KPW * KPW * KOC;
  #pragma unroll
  for (int pc = 0; pc < 4; pc++) {
    int pl = ty * 4 + pc;
    int pp = p0 + pl;
    int yy = pp / KH, xx = pp % KH;
    bf16* row = hp + ((size_t)(yy + 1) * KPW + (xx + 1)) * KOC;
    #pragma unroll
    for (int u = 0; u < 4; u++) row[tx * 4 + u] = __float2bfloat16(T[pl][tx * 4 + u]);
  }
}

// ---------------- conv2 (3x3, 128->128): 128-wide tiles, dy-split dense partials ----------------
__global__ __launch_bounds__(256) void k_conv2(const short* __restrict__ w2p,
                                               const short* __restrict__ hpadT,
                                               float* __restrict__ Cpart) {
  __shared__ short As[128][40];
  __shared__ short Bs[128][40];
  int p0 = blockIdx.x * 128, dy = blockIdx.y, n = blockIdx.z;
  int tid = threadIdx.x, lane = tid & 63, wave = tid >> 6;
  int quad = lane >> 4, l15 = lane & 15;
  int wm = (wave & 1) * 64, wn = (wave >> 1) * 64;
  int ar = tid >> 2, ko = (tid & 3) * 8;
  const short* hb = hpadT + (size_t)n * KPW * KPW * KOC;
  int pr0 = min(p0 + ar, KHW - 1), pr1 = min(p0 + ar + 64, KHW - 1);
  int y0 = pr0 / KH, x0 = pr0 % KH;
  int y1 = pr1 / KH, x1 = pr1 % KH;
  f32x4 acc[4][4] = {};
  for (int dx = 0; dx < 3; ++dx) {
    const short* a0 = w2p + (size_t)ar * 9 * KOC + (dy * 3 + dx) * KOC + ko;
    const short* a1 = w2p + (size_t)(ar + 64) * 9 * KOC + (dy * 3 + dx) * KOC + ko;
    const short* b0 = hb + ((size_t)(y0 + dy) * KPW + (x0 + dx)) * KOC + ko;
    const short* b1 = hb + ((size_t)(y1 + dy) * KPW + (x1 + dx)) * KOC + ko;
    for (int k0 = 0; k0 < KOC; k0 += 32) {
      __syncthreads();
      *(float4*)&As[ar][ko]      = *(const float4*)&a0[k0];
      *(float4*)&As[ar + 64][ko] = *(const float4*)&a1[k0];
      *(float4*)&Bs[ar][ko]      = *(const float4*)&b0[k0];
      *(float4*)&Bs[ar + 64][ko] = *(const float4*)&b1[k0];
      __syncthreads();
      short8 a[4], bb[4];
      #pragma unroll
      for (int t = 0; t < 4; t++) a[t] = *(const short8*)&As[wm + t * 16 + l15][quad * 8];
      #pragma unroll
      for (int t = 0; t < 4; t++) bb[t] = *(const short8*)&Bs[wn + t * 16 + l15][quad * 8];
      #pragma unroll
      for (int ti = 0; ti < 4; ti++)
        #pragma unroll
        for (int tj = 0; tj < 4; tj++)
          acc[ti][tj] = __builtin_amdgcn_mfma_f32_16x16x32_bf16(a[ti], bb[tj], acc[ti][tj], 0, 0, 0);
    }
  }
  float* cb = Cpart + ((size_t)(dy * KN + n)) * KOC * KHW;
  for (int ti = 0; ti < 4; ti++) {
    int o = wm + ti * 16 + quad * 4;
    for (int tj = 0; tj < 4; tj++) {
      int q = p0 + wn + tj * 16 + l15;
      if (q < KHW) {
        #pragma unroll
        for (int r = 0; r < 4; r++)
          cb[(size_t)(o + r) * KHW + q] = acc[ti][tj][r];
      }
    }
  }
}

// out = relu(sum_dy Cpart + b2 + shortcut(Hpart[3]) + bs)
__global__ void k_final2(const float* __restrict__ Cpart, const float* __restrict__ Hpart,
                         const float* __restrict__ b2, const float* __restrict__ bs,
                         float* __restrict__ out) {
  int t = blockIdx.x * 256 + threadIdx.x;
  if (t >= KN * KOC * KHW) return;
  int o = (t / KHW) % KOC;
  const size_t stride = (size_t)KN * KOC * KHW;
  float v = Cpart[t] + Cpart[stride + t] + Cpart[2 * stride + t] +
            Hpart[3 * stride + t] + b2[o] + bs[o];
  out[t] = fmaxf(v, 0.0f);
}

// ---------------- launch ----------------
extern "C" void kernel_launch(void* const* d_in, const int* in_sizes, int n_in,
                              void* d_out, int out_size, void* d_ws, size_t ws_size,
                              hipStream_t stream) {
  const float* feats = (const float*)d_in[0];
  const float* sisms = (const float*)d_in[1];
  const float* w1 = (const float*)d_in[2];
  const float* b1 = (const float*)d_in[3];
  const float* w2 = (const float*)d_in[4];
  const float* b2 = (const float*)d_in[5];
  const float* wsc = (const float*)d_in[6];
  const float* bsc = (const float*)d_in[7];
  float* out = (float*)d_out;

  char* w = (char*)d_ws;
  auto carve = [&](size_t bytes) -> void* {
    void* p = (void*)w;
    w += (bytes + 255) & ~(size_t)255;
    return p;
  };
  bf16* NFT   = (bf16*)carve((size_t)KN * KHW * KC * 2);          // 16.4 MB
  bf16* NFcg  = (bf16*)carve((size_t)KN * KC * KHW * 2);          // 16.4 MB
  bf16* Uc    = (bf16*)carve((size_t)KN * 3 * 128 * 1536 * 2);    // 11.8 MB
  bf16* Usc   = (bf16*)carve((size_t)KN * 128 * 512 * 2);         // 1.3 MB
  bf16* w1s   = (bf16*)carve((size_t)KM * KHW * 2);               // 4.1 MB
  bf16* Zpad  = (bf16*)carve((size_t)KN * KPW * KPW * KC * 2);    // 18.1 MB
  bf16* hpadT = (bf16*)carve((size_t)KN * KPW * KPW * KOC * 2);   // 4.5 MB
  float* Hpart = (float*)carve((size_t)4 * KN * KOC * KHW * 4);   // 32.8 MB
  float* Cpart = (float*)carve((size_t)3 * KN * KOC * KHW * 4);   // 24.6 MB
  bf16* w2p   = (bf16*)carve((size_t)KOC * 9 * KOC * 2);
  double* psbuf = (double*)carve((size_t)4 * KN * KHW * 8);
  double* rnorm = (double*)carve((size_t)KN * KHW * 8);
  double* vpp   = (double*)carve((size_t)KN * KC * 50 * 8);       // 2.05 MB
  double* SIV   = (double*)carve((size_t)KN * KC * 8);
  double* cmp   = (double*)carve((size_t)8 * KN * KN * KHW * 8);  // 10.2 MB
  double* cm    = (double*)carve((size_t)KN * KN * KHW * 8);
  double* tbuf  = (double*)carve((size_t)KN * KN * 8);
  double* CSAd  = (double*)carve((size_t)KN * KHW * 8);
  float* CSAf   = (float*)carve((size_t)KN * KHW * 4);
  int* idxb     = (int*)carve((size_t)KN * KHW * 4);

  hipMemsetAsync(hpadT, 0, (size_t)KN * KPW * KPW * KOC * 2, stream);
  hipMemsetAsync(Zpad, 0, (size_t)KN * KPW * KPW * KC * 2, stream);

  k_rnormp<<<dim3(63, 4), 256, 0, stream>>>(feats, psbuf);
  k_rnormc<<<63, 256, 0, stream>>>(psbuf, rnorm);
  k_nft<<<dim3(50, 16, KN), dim3(32, 8), 0, stream>>>(feats, rnorm, sisms, NFT, vpp);
  k_sivnorm2<<<KN, 512, 0, stream>>>(vpp, SIV);
  k_cmP<<<dim3(7, 8, KN), 256, 0, stream>>>(feats, SIV, cmp);
  k_cmB<<<625, 256, 0, stream>>>(cmp, rnorm, cm);
  k_cmnorm<<<KN * KN, 256, 0, stream>>>(cm);
  k_st<<<KN * KN, 256, 0, stream>>>(cm, tbuf);
  k_csa<<<KN, 256, 0, stream>>>(cm, tbuf, CSAd, CSAf);
  k_rank<<<dim3(7, KN), 256, 0, stream>>>(CSAd, idxb);

  k_prepw1s<<<KM * KHW / 256, 256, 0, stream>>>(w1, wsc, w1s);
  k_prepw2<<<576, 256, 0, stream>>>(w2, w2p);
  k_gath2<<<dim3(50, 16, KN), dim3(32, 8), 0, stream>>>((const short*)NFT, idxb, (short*)NFcg);
  k_zprep<<<KN * KHW * (KC / 4) / 256, 256, 0, stream>>>(NFT, CSAf, Zpad);

  k_gemmU<<<400, 256, 0, stream>>>((const short*)w1s, (const short*)NFcg, Uc, Usc);
  k_convh<<<520, 256, 0, stream>>>((const short*)Uc, (const short*)Usc,
                                   (const short*)Zpad, Hpart);
  k_hprep3<<<dim3(50, KN), dim3(32, 8), 0, stream>>>(Hpart, b1, hpadT);
  k_conv2<<<dim3(13, 3, KN), 256, 0, stream>>>((const short*)w2p, (const short*)hpadT, Cpart);
  k_final2<<<8000, 256, 0, stream>>>(Cpart, Hpart, b2, bsc, out);
}